// Round 16
// baseline (438.225 us; speedup 1.0000x reference)
//
#include <hip/hip_runtime.h>

typedef __attribute__((ext_vector_type(8))) short bf16x8;
typedef __attribute__((ext_vector_type(4))) float f32x4;

#define FP const float* __restrict__

__device__ __forceinline__ short f2bf(float f) {
    unsigned u = __float_as_uint(f);
    u += 0x7fffu + ((u >> 16) & 1u);
    return (short)(u >> 16);
}
__device__ __forceinline__ float bf2f(short s) {
    return __uint_as_float(((unsigned)(unsigned short)s) << 16);
}
__device__ __forceinline__ float v_exp2(float x) { float r; asm("v_exp_f32 %0, %1" : "=v"(r) : "v"(x)); return r; }
__device__ __forceinline__ float v_log2(float x) { float r; asm("v_log_f32 %0, %1" : "=v"(r) : "v"(x)); return r; }

__device__ __forceinline__ float fexp(float x) { return v_exp2(1.44269504f * x); }
__device__ __forceinline__ float sp(float x) {         // exact softplus (BN/softmax path)
    return fmaxf(x, 0.f) + 0.69314718f * v_log2(1.f + v_exp2(-1.44269504f * fabsf(x)));
}
// fast softplus: cubic fit of log2(1+t), abs err ~1e-3 (<< bf16 rounding).
// Used only for the 307M hi/hj evals; halves trans-pipe pressure.
__device__ __forceinline__ float spf(float x) {
    const float t = v_exp2(-1.44269504f * fabsf(x));
    const float p = t * (1.419f + t * (-0.573f + 0.154f * t));
    return fmaxf(x, 0.f) + 0.69314718f * p;
}
__device__ __forceinline__ float silu_f(float x) {
    return x * __builtin_amdgcn_rcpf(1.f + v_exp2(-1.44269504f * x));
}

// A-operand = W^T tile: lane l holds W[k, c0+(l&15)], k = 8*(l>>4)+j. W is [32+,ld] f32.
__device__ __forceinline__ bf16x8 load_wfrag(FP w, int ld, int c0, int l) {
    const int c = c0 + (l & 15);
    const int k0 = 8 * (l >> 4);
    bf16x8 f;
#pragma unroll
    for (int j = 0; j < 8; ++j) f[j] = f2bf(w[(k0 + j) * ld + c]);
    return f;
}

// ---------------------------------------------------------------------------
// kprep: bf16-ize atom (N*32) and ef (E*32) + in-degree histogram/rank (merged)
// ---------------------------------------------------------------------------
__global__ __launch_bounds__(256) void kprep(
    FP atom, FP ef, const int* __restrict__ eidx,
    short* __restrict__ atomb, short* __restrict__ efb,
    int* __restrict__ cnt, int* __restrict__ rank,
    int nA4, int nE4, int E)
{
    const int stride = gridDim.x * 256;
    const int tot = nA4 + nE4 + E;
    for (int t = blockIdx.x * 256 + threadIdx.x; t < tot; t += stride) {
        if (t < nA4) {
            const float4 v = ((const float4*)atom)[t];
            short4 s = { f2bf(v.x), f2bf(v.y), f2bf(v.z), f2bf(v.w) };
            ((short4*)atomb)[t] = s;
        } else if (t < nA4 + nE4) {
            const float4 v = ((const float4*)ef)[t - nA4];
            short4 s = { f2bf(v.x), f2bf(v.y), f2bf(v.z), f2bf(v.w) };
            ((short4*)efb)[t - nA4] = s;
        } else {
            const int e = t - nA4 - nE4;
            rank[e] = atomicAdd(&cnt[eidx[e]], 1);
        }
    }
}

// kscanA: per-block sum of cnt -> part[b]
__global__ __launch_bounds__(256) void kscanA(
    const int* __restrict__ cnt, int* __restrict__ part, int N)
{
    __shared__ int wsum[4];
    const int t = threadIdx.x;
    const int i = blockIdx.x * 256 + t;
    int v = (i < N) ? cnt[i] : 0;
#pragma unroll
    for (int d = 1; d < 64; d <<= 1) v += __shfl_xor(v, d);
    if ((t & 63) == 0) wsum[t >> 6] = v;
    __syncthreads();
    if (t == 0) part[blockIdx.x] = wsum[0] + wsum[1] + wsum[2] + wsum[3];
}

// kscanB: single block exclusive scan over nb partials (nb <= 1024)
__global__ __launch_bounds__(1024) void kscanB(
    int* __restrict__ part, int nb)
{
    __shared__ int pa[1024], pb[1024];
    const int t = threadIdx.x;
    pa[t] = (t < nb) ? part[t] : 0;
    __syncthreads();
    int* src = pa; int* dst = pb;
#pragma unroll
    for (int d = 1; d < 1024; d <<= 1) {
        int v = src[t];
        if (t >= d) v += src[t - d];
        dst[t] = v;
        __syncthreads();
        int* tmp = src; src = dst; dst = tmp;
    }
    if (t < nb) part[t] = (t == 0) ? 0 : src[t - 1];
}

// kscanC: block-local scan + base -> off[i]; last element writes off[N]
__global__ __launch_bounds__(256) void kscanC(
    const int* __restrict__ cnt, const int* __restrict__ part,
    int* __restrict__ off, int N)
{
    __shared__ int pa[256], pb[256];
    const int t = threadIdx.x;
    const int i = blockIdx.x * 256 + t;
    const int c = (i < N) ? cnt[i] : 0;
    pa[t] = c;
    __syncthreads();
    int* src = pa; int* dst = pb;
#pragma unroll
    for (int d = 1; d < 256; d <<= 1) {
        int v = src[t];
        if (t >= d) v += src[t - d];
        dst[t] = v;
        __syncthreads();
        int* tmp = src; src = dst; dst = tmp;
    }
    const int incl = src[t];
    const int base = part[blockIdx.x];
    if (i < N) off[i] = base + incl - c;
    if (i == N - 1) off[N] = base + incl;
}

// ---------------------------------------------------------------------------
// kBc: 2-tile ILP: both tiles' gathers issue before compute; each LDS weight
// read feeds 6 MFMAs. Poly softplus on hi/hj. BN -> padded per-block partials.
// ---------------------------------------------------------------------------
__global__ __launch_bounds__(256, 4) void kBc(
    const short* __restrict__ efb, const int* __restrict__ eidx,
    const short* __restrict__ atomb, FP Wg, FP attg,
    float* __restrict__ alpha, float* __restrict__ bnpart, int E)
{
    __shared__ float attl[256];
    __shared__ __align__(16) short Wl[16][64][8];   // 16 KB
    __shared__ float bnred[4][8];
    const int t = threadIdx.x;
    if (t < 64) ((float4*)attl)[t] = ((const float4*)attg)[t];
    for (int s = t; s < 1024; s += 256) {
        const int f = s >> 6, ll = s & 63;
        FP src = (f < 8) ? Wg : (Wg + 32 * 128);
        bf16x8 fr = load_wfrag(src, 128, 16 * (f & 7), ll);
        *(bf16x8*)&Wl[f][ll][0] = fr;
    }
    __syncthreads();

    const int l = t & 63, q = l >> 4, e15 = l & 15, wvb = t >> 6;
    const int wv = blockIdx.x * 4 + wvb, nw = gridDim.x * 4;
    const f32x4 z = {0.f, 0.f, 0.f, 0.f};
    float bs[4] = {0,0,0,0}, bq2[4] = {0,0,0,0};

    const int nt = E >> 4;
    for (int base = wv; base < nt; base += 2 * nw) {
        const int t0 = base;
        const bool has1 = (base + nw) < nt;
        const int t1 = has1 ? (base + nw) : base;
        const int e0 = t0 * 16 + e15, e1 = t1 * 16 + e15;
        const int i0 = eidx[e0], j0 = eidx[E + e0];
        const int i1 = eidx[e1], j1 = eidx[E + e1];
        const bf16x8 xi0 = *(const bf16x8*)&atomb[(size_t)i0 * 32 + 8 * q];
        const bf16x8 xj0 = *(const bf16x8*)&atomb[(size_t)j0 * 32 + 8 * q];
        const bf16x8 xe0 = *(const bf16x8*)&efb[(size_t)e0 * 32 + 8 * q];
        const bf16x8 xi1 = *(const bf16x8*)&atomb[(size_t)i1 * 32 + 8 * q];
        const bf16x8 xj1 = *(const bf16x8*)&atomb[(size_t)j1 * 32 + 8 * q];
        const bf16x8 xe1 = *(const bf16x8*)&efb[(size_t)e1 * 32 + 8 * q];

        float ph0[4] = {0,0,0,0}, ph1[4] = {0,0,0,0};
#pragma unroll
        for (int mb = 0; mb < 8; ++mb) {
            const bf16x8 wa = *(const bf16x8*)&Wl[mb][l][0];
            const bf16x8 we = *(const bf16x8*)&Wl[8 + mb][l][0];
            const f32x4 ee0 = __builtin_amdgcn_mfma_f32_16x16x32_bf16(we, xe0, z, 0, 0, 0);
            const f32x4 ha0 = __builtin_amdgcn_mfma_f32_16x16x32_bf16(wa, xi0, z, 0, 0, 0);
            const f32x4 hb0 = __builtin_amdgcn_mfma_f32_16x16x32_bf16(wa, xj0, z, 0, 0, 0);
            const f32x4 ee1 = __builtin_amdgcn_mfma_f32_16x16x32_bf16(we, xe1, z, 0, 0, 0);
            const f32x4 ha1 = __builtin_amdgcn_mfma_f32_16x16x32_bf16(wa, xi1, z, 0, 0, 0);
            const f32x4 hb1 = __builtin_amdgcn_mfma_f32_16x16x32_bf16(wa, xj1, z, 0, 0, 0);
            const int h = mb >> 1;
            const int c0 = (mb & 1) * 16 + 4 * q;
#pragma unroll
            for (int r = 0; r < 4; ++r) {
                const float a1v = attl[h * 64 + c0 + r];
                const float a2v = attl[h * 64 + 32 + c0 + r];
                ph0[h] += spf(ha0[r] + ee0[r]) * a1v + spf(hb0[r] + ee0[r]) * a2v;
                ph1[h] += spf(ha1[r] + ee1[r]) * a1v + spf(hb1[r] + ee1[r]) * a2v;
            }
        }
        float4 a0v0, a0v1;
#pragma unroll
        for (int h = 0; h < 4; ++h) {
            float v0 = ph0[h], v1 = ph1[h];
            v0 += __shfl_xor(v0, 16); v1 += __shfl_xor(v1, 16);
            v0 += __shfl_xor(v0, 32); v1 += __shfl_xor(v1, 32);
            (&a0v0.x)[h] = sp(v0);
            (&a0v1.x)[h] = sp(v1);
        }
        if (q == 0) {
            *(float4*)&alpha[(size_t)e0 * 4] = a0v0;
#pragma unroll
            for (int h = 0; h < 4; ++h) {
                const float a0 = (&a0v0.x)[h];
                bs[h] += a0; bq2[h] += a0 * a0;
            }
            if (has1) {
                *(float4*)&alpha[(size_t)e1 * 4] = a0v1;
#pragma unroll
                for (int h = 0; h < 4; ++h) {
                    const float a0 = (&a0v1.x)[h];
                    bs[h] += a0; bq2[h] += a0 * a0;
                }
            }
        }
    }
#pragma unroll
    for (int h = 0; h < 4; ++h) {
        float v = bs[h], w = bq2[h];
#pragma unroll
        for (int d = 1; d < 64; d <<= 1) { v += __shfl_xor(v, d); w += __shfl_xor(w, d); }
        if (l == 0) { bnred[wvb][h] = v; bnred[wvb][4 + h] = w; }
    }
    __syncthreads();
    if (t < 8) {
        const float s = bnred[0][t] + bnred[1][t] + bnred[2][t] + bnred[3][t];
        bnpart[(size_t)blockIdx.x * 16 + t] = s;
    }
}

// k2: reduce per-block BN partials, finalize scale/shift
__global__ __launch_bounds__(256) void k2_bn(
    const float* __restrict__ bnpart, int nblk, FP gam, FP bet,
    float* __restrict__ bnsc, int E)
{
    __shared__ float red[256];
    const int t = threadIdx.x;
    const int h = t & 7, c = t >> 3;
    float s = 0.f;
    for (int b = c; b < nblk; b += 32) s += bnpart[(size_t)b * 16 + h];
    red[t] = s;
    __syncthreads();
    if (t < 8) {
        float acc = 0.f;
#pragma unroll
        for (int c2 = 0; c2 < 32; ++c2) acc += red[c2 * 8 + t];
        red[t] = acc;
    }
    __syncthreads();
    if (t < 4) {
        const float inv = 1.f / (float)E;
        const float mu  = red[t] * inv;
        const float var = red[4 + t] * inv - mu * mu;
        const float scl = gam[t] * rsqrtf(var + 1e-5f);
        bnsc[t] = scl;
        bnsc[4 + t] = bet[t] - mu * scl;
    }
}

// k34: alpha -> ex = exp(sp(scale*alpha+shift)) in place; distributed seg-sum.
__global__ __launch_bounds__(256) void k34(
    float* __restrict__ alpha, const int* __restrict__ eidx,
    float* __restrict__ sbuf, const float* __restrict__ bnsc, int E)
{
    const int t = blockIdx.x * 256 + threadIdx.x;
    if (t >= 4 * E) return;
    const int e = t >> 2, h = t & 3;
    const float a1 = sp(bnsc[h] * alpha[t] + bnsc[4 + h]);
    const float ex = fexp(a1);
    alpha[t] = ex;
    atomicAdd(&sbuf[eidx[e] * 4 + h], ex);
}

// ---------------------------------------------------------------------------
// kmsg3: 2-tile ILP; poly softplus on hj; plain scatter store, NO atomics.
// ---------------------------------------------------------------------------
__global__ __launch_bounds__(256, 4) void kmsg3(
    const short* __restrict__ efb, const int* __restrict__ eidx,
    const short* __restrict__ atomb, const int* __restrict__ off,
    const int* __restrict__ rank, FP Wg,
    const float* __restrict__ alpha, const float* __restrict__ sbuf,
    short* __restrict__ msg, int E)
{
    __shared__ __align__(16) short Wl[16][64][8];   // 16 KB
    const int t = threadIdx.x;
    for (int s = t; s < 1024; s += 256) {
        const int f = s >> 6, ll = s & 63;
        FP src = (f < 8) ? Wg : (Wg + 32 * 128);
        bf16x8 fr = load_wfrag(src, 128, 16 * (f & 7), ll);
        *(bf16x8*)&Wl[f][ll][0] = fr;
    }
    __syncthreads();

    const int l = t & 63, q = l >> 4, e15 = l & 15;
    const int wv = blockIdx.x * 4 + (t >> 6), nw = gridDim.x * 4;
    const f32x4 z = {0.f, 0.f, 0.f, 0.f};

    const int nt = E >> 4;
    for (int base = wv; base < nt; base += 2 * nw) {
        const bool has1 = (base + nw) < nt;
        const int t1 = has1 ? (base + nw) : base;
        const int e0 = base * 16 + e15, e1 = t1 * 16 + e15;
        const int i0 = eidx[e0], j0 = eidx[E + e0];
        const int i1 = eidx[e1], j1 = eidx[E + e1];
        const int d0 = off[i0] + rank[e0];
        const int d1 = off[i1] + rank[e1];
        const bf16x8 xj0 = *(const bf16x8*)&atomb[(size_t)j0 * 32 + 8 * q];
        const bf16x8 xe0 = *(const bf16x8*)&efb[(size_t)e0 * 32 + 8 * q];
        const bf16x8 xj1 = *(const bf16x8*)&atomb[(size_t)j1 * 32 + 8 * q];
        const bf16x8 xe1 = *(const bf16x8*)&efb[(size_t)e1 * 32 + 8 * q];
        const float4 a40 = *(const float4*)&alpha[(size_t)e0 * 4];
        const float4 s40 = *(const float4*)&sbuf[(size_t)i0 * 4];
        const float4 a41 = *(const float4*)&alpha[(size_t)e1 * 4];
        const float4 s41 = *(const float4*)&sbuf[(size_t)i1 * 4];
        float af0[4], af1[4];
#pragma unroll
        for (int h = 0; h < 4; ++h) {
            af0[h] = (&a40.x)[h] * __builtin_amdgcn_rcpf((&s40.x)[h] + 1e-16f);
            af1[h] = (&a41.x)[h] * __builtin_amdgcn_rcpf((&s41.x)[h] + 1e-16f);
        }

        float c40[8] = {0,0,0,0,0,0,0,0}, c41[8] = {0,0,0,0,0,0,0,0};
#pragma unroll
        for (int mb = 0; mb < 8; ++mb) {
            const bf16x8 wa = *(const bf16x8*)&Wl[mb][l][0];
            const bf16x8 we = *(const bf16x8*)&Wl[8 + mb][l][0];
            const f32x4 ee0 = __builtin_amdgcn_mfma_f32_16x16x32_bf16(we, xe0, z, 0, 0, 0);
            const f32x4 hb0 = __builtin_amdgcn_mfma_f32_16x16x32_bf16(wa, xj0, z, 0, 0, 0);
            const f32x4 ee1 = __builtin_amdgcn_mfma_f32_16x16x32_bf16(we, xe1, z, 0, 0, 0);
            const f32x4 hb1 = __builtin_amdgcn_mfma_f32_16x16x32_bf16(wa, xj1, z, 0, 0, 0);
            const float a0 = af0[mb >> 1], a1 = af1[mb >> 1];
            const int s = (mb & 1) * 4;
#pragma unroll
            for (int r = 0; r < 4; ++r) {
                c40[s + r] += spf(hb0[r] + ee0[r]) * a0;
                c41[s + r] += spf(hb1[r] + ee1[r]) * a1;
            }
        }
#pragma unroll
        for (int s2 = 0; s2 < 2; ++s2) {
            short4 pk0 = { f2bf(c40[s2*4+0]), f2bf(c40[s2*4+1]), f2bf(c40[s2*4+2]), f2bf(c40[s2*4+3]) };
            *(short4*)&msg[(size_t)d0 * 32 + s2 * 16 + 4 * q] = pk0;
            if (has1) {
                short4 pk1 = { f2bf(c41[s2*4+0]), f2bf(c41[s2*4+1]), f2bf(c41[s2*4+2]), f2bf(c41[s2*4+3]) };
                *(short4*)&msg[(size_t)d1 * 32 + s2 * 16 + 4 * q] = pk1;
            }
        }
    }
}

// kred: per node, stream its sorted msg rows, x0.25, +bias -> outp (f32) + outb (bf16)
__global__ __launch_bounds__(256) void kred(
    const int* __restrict__ off, const short* __restrict__ msg, FP bias,
    float* __restrict__ outp, short* __restrict__ outb, int N)
{
    const int lane = threadIdx.x & 31;
    const int sub = threadIdx.x >> 5;
    const float b = bias[lane];
    for (int node = blockIdx.x * 8 + sub; node < N; node += gridDim.x * 8) {
        const int o0 = off[node], o1 = off[node + 1];
        float acc = 0.f;
        for (int p = o0; p < o1; ++p) acc += bf2f(msg[(size_t)p * 32 + lane]);
        const float v = 0.25f * acc + b;
        outp[(size_t)node * 32 + lane] = v;
        outb[(size_t)node * 32 + lane] = f2bf(v);
    }
}

// ---------------------------------------------------------------------------
// kG2v: edge MLP. Interleaved silu->MFMA per kc slice (hs = 5.1 KB; LDS 38.5 KB
// -> 4 blocks/CU). (256,2): a1[8]+xb need ~88 VGPR (the (256,4) cap spilled).
// ---------------------------------------------------------------------------
__global__ __launch_bounds__(256, 2) void kG2v(
    const short* __restrict__ efb, const int* __restrict__ eidx,
    const short* __restrict__ outb,
    FP W1g, FP W2, FP b1g, FP b2g, float* __restrict__ eout, int E)
{
    __shared__ __align__(16) short W1f[3][8][64][8];   // 24 KB
    __shared__ __align__(16) short W2f[8][64][8];      // 8 KB
    __shared__ float b1l[128];
    __shared__ float b2l[32];
    __shared__ __align__(16) short hs[4][16 * 40];     // 5.1 KB: one kc slice/wave
    const int t = threadIdx.x;
    for (int s = t; s < 3 * 8 * 64; s += 256) {
        const int ks = s >> 9, rem = s & 511, mb = rem >> 6, ll = rem & 63;
        const int c = 16 * mb + (ll & 15);
        const int k0 = ks * 32 + 8 * (ll >> 4);
        bf16x8 f;
#pragma unroll
        for (int j = 0; j < 8; ++j) f[j] = f2bf(W1g[(size_t)(k0 + j) * 128 + c]);
        *(bf16x8*)&W1f[ks][mb][ll][0] = f;
    }
    for (int s = t; s < 8 * 64; s += 256) {
        const int f = s >> 6, ll = s & 63;
        const int kc = f >> 1, m2 = f & 1;
        bf16x8 fr = load_wfrag(W2 + 32 * kc * 32, 32, 16 * m2, ll);
        *(bf16x8*)&W2f[f][ll][0] = fr;
    }
    if (t < 128) b1l[t] = b1g[t];
    if (t < 32)  b2l[t] = b2g[t];
    __syncthreads();

    const int l = t & 63, q = l >> 4, e15 = l & 15, wvb = t >> 6;
    short* hw = &hs[wvb][0];
    const f32x4 z = {0.f, 0.f, 0.f, 0.f};

    const int wv = blockIdx.x * 4 + wvb, nw = gridDim.x * 4, nt = E >> 4;
    for (int tt = wv; tt < nt; tt += nw) {
        const int tb = tt * 16;
        const int e = tb + e15;
        const int ri = eidx[e], ci = eidx[E + e];
        bf16x8 xb[3];
        xb[0] = *(const bf16x8*)&outb[(size_t)ri * 32 + 8 * q];
        xb[1] = *(const bf16x8*)&outb[(size_t)ci * 32 + 8 * q];
        xb[2] = *(const bf16x8*)&efb[(size_t)e * 32 + 8 * q];

        f32x4 a1[8] = {z, z, z, z, z, z, z, z};
#pragma unroll
        for (int ks = 0; ks < 3; ++ks)
#pragma unroll
            for (int mb = 0; mb < 8; ++mb) {
                const bf16x8 wfr = *(const bf16x8*)&W1f[ks][mb][l][0];
                a1[mb] = __builtin_amdgcn_mfma_f32_16x16x32_bf16(wfr, xb[ks], a1[mb], 0, 0, 0);
            }
        f32x4 oc0 = z, oc1 = z;
#pragma unroll
        for (int kc = 0; kc < 4; ++kc) {
#pragma unroll
            for (int half = 0; half < 2; ++half) {
                const int mb = 2 * kc + half;
                short4 s;
                s.x = f2bf(silu_f(a1[mb][0] + b1l[16 * mb + 4 * q + 0]));
                s.y = f2bf(silu_f(a1[mb][1] + b1l[16 * mb + 4 * q + 1]));
                s.z = f2bf(silu_f(a1[mb][2] + b1l[16 * mb + 4 * q + 2]));
                s.w = f2bf(silu_f(a1[mb][3] + b1l[16 * mb + 4 * q + 3]));
                *(short4*)&hw[e15 * 40 + half * 16 + 4 * q] = s;   // wave-internal, in-order DS
            }
            const bf16x8 hf = *(const bf16x8*)&hw[e15 * 40 + 8 * q];
            const bf16x8 w20 = *(const bf16x8*)&W2f[kc * 2][l][0];
            const bf16x8 w21 = *(const bf16x8*)&W2f[kc * 2 + 1][l][0];
            oc0 = __builtin_amdgcn_mfma_f32_16x16x32_bf16(w20, hf, oc0, 0, 0, 0);
            oc1 = __builtin_amdgcn_mfma_f32_16x16x32_bf16(w21, hf, oc1, 0, 0, 0);
        }
        float4 o0, o1;
#pragma unroll
        for (int r = 0; r < 4; ++r) {
            (&o0.x)[r] = silu_f(oc0[r] + b2l[4 * q + r]);
            (&o1.x)[r] = silu_f(oc1[r] + b2l[16 + 4 * q + r]);
        }
        *(float4*)&eout[(size_t)e * 32 + 4 * q] = o0;
        *(float4*)&eout[(size_t)e * 32 + 16 + 4 * q] = o1;
    }
}

extern "C" void kernel_launch(void* const* d_in, const int* in_sizes, int n_in,
                              void* d_out, int out_size, void* d_ws, size_t ws_size,
                              hipStream_t stream)
{
    const float* atom = (const float*)d_in[0];
    const int*   eidx = (const int*)d_in[1];
    const float* efea = (const float*)d_in[2];
    const float* Wg   = (const float*)d_in[6];
    const float* attg = (const float*)d_in[7];
    const float* bias = (const float*)d_in[8];
    const float* gam  = (const float*)d_in[9];
    const float* bet  = (const float*)d_in[10];
    const float* W1g  = (const float*)d_in[11];
    const float* b1g  = (const float*)d_in[12];
    const float* W2g  = (const float*)d_in[13];
    const float* b2g  = (const float*)d_in[14];

    const int N = in_sizes[0] / 32;
    const int E = in_sizes[2] / 32;
    const int NBLK = 4096;
    const int nbs = (N + 255) >> 8;               // scan blocks

    // workspace layout (f32 units, 16B-aligned sections)
    float* ws = (float*)d_ws;
    size_t o = 0;
    float* sbuf   = ws + o;          o += (size_t)4 * N;   // zeroed
    int*   cnt    = (int*)(ws + o);  o += N;               // zeroed
    float* bnsc   = ws + o;          o += 8;
    int*   off    = (int*)(ws + o);  o += (size_t)N + 1;
    o = (o + 3) & ~(size_t)3;
    int*   rank   = (int*)(ws + o);  o += E;
    int*   part   = (int*)(ws + o);  o += (size_t)nbs + 4;
    o = (o + 3) & ~(size_t)3;
    float* bnpart = ws + o;          o += (size_t)NBLK * 16;
    o = (o + 7) & ~(size_t)7;
    short* atomb  = (short*)(ws + o); o += (size_t)N * 16;   // N*32 bf16
    short* efb    = (short*)(ws + o); o += (size_t)E * 16;   // E*32 bf16
    short* outb   = (short*)(ws + o); o += (size_t)N * 16;   // N*32 bf16

    // d_out: [out N*32 f32][eout E*32 f32]; eout region = alpha + msg scratch
    float* outp  = (float*)d_out;
    float* scratch = outp + (size_t)N * 32;
    float* alpha = scratch;                          // 4E f32
    short* msg   = (short*)(scratch + (size_t)4 * E);// E*32 bf16 (sorted messages)
    float* eout  = scratch;                          // written last by kG2v

    hipMemsetAsync(ws, 0, (size_t)5 * N * sizeof(float), stream);  // sbuf,cnt

    const int n4e = 4 * E;
    kprep<<<2048, 256, 0, stream>>>(atom, efea, eidx, atomb, efb, cnt, rank, N * 8, E * 8, E);
    kscanA<<<nbs, 256, 0, stream>>>(cnt, part, N);
    kscanB<<<1, 1024, 0, stream>>>(part, nbs);
    kscanC<<<nbs, 256, 0, stream>>>(cnt, part, off, N);
    kBc  <<<NBLK, 256, 0, stream>>>(efb, eidx, atomb, Wg, attg, alpha, bnpart, E);
    k2_bn<<<1, 256, 0, stream>>>(bnpart, NBLK, gam, bet, bnsc, E);
    k34  <<<(n4e + 255) / 256, 256, 0, stream>>>(alpha, eidx, sbuf, bnsc, E);
    kmsg3<<<4096, 256, 0, stream>>>(efb, eidx, atomb, off, rank, Wg, alpha, sbuf, msg, E);
    kred <<<4096, 256, 0, stream>>>(off, msg, bias, outp, outb, N);
    kG2v <<<2048, 256, 0, stream>>>(efb, eidx, outb, W1g, W2g, b1g, b2g, eout, E);
}

// Round 17
// 373.647 us; speedup vs baseline: 1.1728x; 1.1728x over previous
//
#include <hip/hip_runtime.h>

typedef __attribute__((ext_vector_type(8))) short bf16x8;
typedef __attribute__((ext_vector_type(4))) float f32x4;

#define FP const float* __restrict__

__device__ __forceinline__ short f2bf(float f) {
    unsigned u = __float_as_uint(f);
    u += 0x7fffu + ((u >> 16) & 1u);
    return (short)(u >> 16);
}
__device__ __forceinline__ float bf2f(short s) {
    return __uint_as_float(((unsigned)(unsigned short)s) << 16);
}
__device__ __forceinline__ float v_exp2(float x) { float r; asm("v_exp_f32 %0, %1" : "=v"(r) : "v"(x)); return r; }
__device__ __forceinline__ float v_log2(float x) { float r; asm("v_log_f32 %0, %1" : "=v"(r) : "v"(x)); return r; }

__device__ __forceinline__ float fexp(float x) { return v_exp2(1.44269504f * x); }
__device__ __forceinline__ float sp(float x) {         // exact softplus (BN/softmax path)
    return fmaxf(x, 0.f) + 0.69314718f * v_log2(1.f + v_exp2(-1.44269504f * fabsf(x)));
}
// fast softplus: cubic fit of log2(1+t), abs err ~1e-3 (<< bf16 rounding).
__device__ __forceinline__ float spf(float x) {
    const float t = v_exp2(-1.44269504f * fabsf(x));
    const float p = t * (1.419f + t * (-0.573f + 0.154f * t));
    return fmaxf(x, 0.f) + 0.69314718f * p;
}
__device__ __forceinline__ float silu_f(float x) {
    return x * __builtin_amdgcn_rcpf(1.f + v_exp2(-1.44269504f * x));
}

// A-operand = W^T tile: lane l holds W[k, c0+(l&15)], k = 8*(l>>4)+j. W is [32+,ld] f32.
__device__ __forceinline__ bf16x8 load_wfrag(FP w, int ld, int c0, int l) {
    const int c = c0 + (l & 15);
    const int k0 = 8 * (l >> 4);
    bf16x8 f;
#pragma unroll
    for (int j = 0; j < 8; ++j) f[j] = f2bf(w[(k0 + j) * ld + c]);
    return f;
}

// ---------------------------------------------------------------------------
// kprep: bf16-ize atom (N*32) and ef (E*32) + in-degree histogram/rank (merged)
// ---------------------------------------------------------------------------
__global__ __launch_bounds__(256) void kprep(
    FP atom, FP ef, const int* __restrict__ eidx,
    short* __restrict__ atomb, short* __restrict__ efb,
    int* __restrict__ cnt, int* __restrict__ rank,
    int nA4, int nE4, int E)
{
    const int stride = gridDim.x * 256;
    const int tot = nA4 + nE4 + E;
    for (int t = blockIdx.x * 256 + threadIdx.x; t < tot; t += stride) {
        if (t < nA4) {
            const float4 v = ((const float4*)atom)[t];
            short4 s = { f2bf(v.x), f2bf(v.y), f2bf(v.z), f2bf(v.w) };
            ((short4*)atomb)[t] = s;
        } else if (t < nA4 + nE4) {
            const float4 v = ((const float4*)ef)[t - nA4];
            short4 s = { f2bf(v.x), f2bf(v.y), f2bf(v.z), f2bf(v.w) };
            ((short4*)efb)[t - nA4] = s;
        } else {
            const int e = t - nA4 - nE4;
            rank[e] = atomicAdd(&cnt[eidx[e]], 1);
        }
    }
}

// kscanA: per-block sum of cnt -> part[b]
__global__ __launch_bounds__(256) void kscanA(
    const int* __restrict__ cnt, int* __restrict__ part, int N)
{
    __shared__ int wsum[4];
    const int t = threadIdx.x;
    const int i = blockIdx.x * 256 + t;
    int v = (i < N) ? cnt[i] : 0;
#pragma unroll
    for (int d = 1; d < 64; d <<= 1) v += __shfl_xor(v, d);
    if ((t & 63) == 0) wsum[t >> 6] = v;
    __syncthreads();
    if (t == 0) part[blockIdx.x] = wsum[0] + wsum[1] + wsum[2] + wsum[3];
}

// kscanB: single block exclusive scan over nb partials (nb <= 1024)
__global__ __launch_bounds__(1024) void kscanB(
    int* __restrict__ part, int nb)
{
    __shared__ int pa[1024], pb[1024];
    const int t = threadIdx.x;
    pa[t] = (t < nb) ? part[t] : 0;
    __syncthreads();
    int* src = pa; int* dst = pb;
#pragma unroll
    for (int d = 1; d < 1024; d <<= 1) {
        int v = src[t];
        if (t >= d) v += src[t - d];
        dst[t] = v;
        __syncthreads();
        int* tmp = src; src = dst; dst = tmp;
    }
    if (t < nb) part[t] = (t == 0) ? 0 : src[t - 1];
}

// kscanC: block-local scan + base -> off[i]; last element writes off[N]
__global__ __launch_bounds__(256) void kscanC(
    const int* __restrict__ cnt, const int* __restrict__ part,
    int* __restrict__ off, int N)
{
    __shared__ int pa[256], pb[256];
    const int t = threadIdx.x;
    const int i = blockIdx.x * 256 + t;
    const int c = (i < N) ? cnt[i] : 0;
    pa[t] = c;
    __syncthreads();
    int* src = pa; int* dst = pb;
#pragma unroll
    for (int d = 1; d < 256; d <<= 1) {
        int v = src[t];
        if (t >= d) v += src[t - d];
        dst[t] = v;
        __syncthreads();
        int* tmp = src; src = dst; dst = tmp;
    }
    const int incl = src[t];
    const int base = part[blockIdx.x];
    if (i < N) off[i] = base + incl - c;
    if (i == N - 1) off[N] = base + incl;
}

// ---------------------------------------------------------------------------
// kBc: single-tile (R15 form; R16's 2-tile ILP forced remat at VGPR=56 and
// regressed). Inline-gather from L2-resident atomb; weights in LDS; spf.
// ---------------------------------------------------------------------------
__global__ __launch_bounds__(256, 4) void kBc(
    const short* __restrict__ efb, const int* __restrict__ eidx,
    const short* __restrict__ atomb, FP Wg, FP attg,
    float* __restrict__ alpha, float* __restrict__ bnpart, int E)
{
    __shared__ float attl[256];
    __shared__ __align__(16) short Wl[16][64][8];   // 16 KB
    __shared__ float bnred[4][8];
    const int t = threadIdx.x;
    if (t < 64) ((float4*)attl)[t] = ((const float4*)attg)[t];
    for (int s = t; s < 1024; s += 256) {
        const int f = s >> 6, ll = s & 63;
        FP src = (f < 8) ? Wg : (Wg + 32 * 128);
        bf16x8 fr = load_wfrag(src, 128, 16 * (f & 7), ll);
        *(bf16x8*)&Wl[f][ll][0] = fr;
    }
    __syncthreads();

    const int l = t & 63, q = l >> 4, e15 = l & 15, wvb = t >> 6;
    const int wv = blockIdx.x * 4 + wvb, nw = gridDim.x * 4;
    const f32x4 z = {0.f, 0.f, 0.f, 0.f};
    float bs[4] = {0,0,0,0}, bq2[4] = {0,0,0,0};

    const int nt = E >> 4;
    for (int tt = wv; tt < nt; tt += nw) {
        const int tb = tt * 16;
        const int e = tb + e15;
        const int i = eidx[e], j = eidx[E + e];
        const bf16x8 xi = *(const bf16x8*)&atomb[(size_t)i * 32 + 8 * q];
        const bf16x8 xj = *(const bf16x8*)&atomb[(size_t)j * 32 + 8 * q];
        const bf16x8 xe = *(const bf16x8*)&efb[(size_t)e * 32 + 8 * q];

        float ph[4] = {0,0,0,0};
#pragma unroll
        for (int mb = 0; mb < 8; ++mb) {
            const bf16x8 wa = *(const bf16x8*)&Wl[mb][l][0];
            const bf16x8 we = *(const bf16x8*)&Wl[8 + mb][l][0];
            const f32x4 ee = __builtin_amdgcn_mfma_f32_16x16x32_bf16(we, xe, z, 0, 0, 0);
            const f32x4 ha = __builtin_amdgcn_mfma_f32_16x16x32_bf16(wa, xi, z, 0, 0, 0);
            const f32x4 hb = __builtin_amdgcn_mfma_f32_16x16x32_bf16(wa, xj, z, 0, 0, 0);
            const int h = mb >> 1;
            const int c0 = (mb & 1) * 16 + 4 * q;
#pragma unroll
            for (int r = 0; r < 4; ++r) {
                ph[h] += spf(ha[r] + ee[r]) * attl[h * 64 + c0 + r]
                       + spf(hb[r] + ee[r]) * attl[h * 64 + 32 + c0 + r];
            }
        }
        float4 a0v;
#pragma unroll
        for (int h = 0; h < 4; ++h) {
            float v = ph[h];
            v += __shfl_xor(v, 16);
            v += __shfl_xor(v, 32);
            (&a0v.x)[h] = sp(v);
        }
        if (q == 0) {
            *(float4*)&alpha[(size_t)e * 4] = a0v;
#pragma unroll
            for (int h = 0; h < 4; ++h) {
                const float a0 = (&a0v.x)[h];
                bs[h] += a0; bq2[h] += a0 * a0;
            }
        }
    }
#pragma unroll
    for (int h = 0; h < 4; ++h) {
        float v = bs[h], w = bq2[h];
#pragma unroll
        for (int d = 1; d < 64; d <<= 1) { v += __shfl_xor(v, d); w += __shfl_xor(w, d); }
        if (l == 0) { bnred[wvb][h] = v; bnred[wvb][4 + h] = w; }
    }
    __syncthreads();
    if (t < 8) {
        const float s = bnred[0][t] + bnred[1][t] + bnred[2][t] + bnred[3][t];
        bnpart[(size_t)blockIdx.x * 16 + t] = s;
    }
}

// k2: reduce per-block BN partials, finalize scale/shift
__global__ __launch_bounds__(256) void k2_bn(
    const float* __restrict__ bnpart, int nblk, FP gam, FP bet,
    float* __restrict__ bnsc, int E)
{
    __shared__ float red[256];
    const int t = threadIdx.x;
    const int h = t & 7, c = t >> 3;
    float s = 0.f;
    for (int b = c; b < nblk; b += 32) s += bnpart[(size_t)b * 16 + h];
    red[t] = s;
    __syncthreads();
    if (t < 8) {
        float acc = 0.f;
#pragma unroll
        for (int c2 = 0; c2 < 32; ++c2) acc += red[c2 * 8 + t];
        red[t] = acc;
    }
    __syncthreads();
    if (t < 4) {
        const float inv = 1.f / (float)E;
        const float mu  = red[t] * inv;
        const float var = red[4 + t] * inv - mu * mu;
        const float scl = gam[t] * rsqrtf(var + 1e-5f);
        bnsc[t] = scl;
        bnsc[4 + t] = bet[t] - mu * scl;
    }
}

// k34: alpha -> ex = exp(sp(scale*alpha+shift)) in place; distributed seg-sum.
__global__ __launch_bounds__(256) void k34(
    float* __restrict__ alpha, const int* __restrict__ eidx,
    float* __restrict__ sbuf, const float* __restrict__ bnsc, int E)
{
    const int t = blockIdx.x * 256 + threadIdx.x;
    if (t >= 4 * E) return;
    const int e = t >> 2, h = t & 3;
    const float a1 = sp(bnsc[h] * alpha[t] + bnsc[4 + h]);
    const float ex = fexp(a1);
    alpha[t] = ex;
    atomicAdd(&sbuf[eidx[e] * 4 + h], ex);
}

// ---------------------------------------------------------------------------
// kmsg3: single-tile (R15 form); inline-gather xj; spf; plain scatter store.
// ---------------------------------------------------------------------------
__global__ __launch_bounds__(256, 4) void kmsg3(
    const short* __restrict__ efb, const int* __restrict__ eidx,
    const short* __restrict__ atomb, const int* __restrict__ off,
    const int* __restrict__ rank, FP Wg,
    const float* __restrict__ alpha, const float* __restrict__ sbuf,
    short* __restrict__ msg, int E)
{
    __shared__ __align__(16) short Wl[16][64][8];   // 16 KB
    const int t = threadIdx.x;
    for (int s = t; s < 1024; s += 256) {
        const int f = s >> 6, ll = s & 63;
        FP src = (f < 8) ? Wg : (Wg + 32 * 128);
        bf16x8 fr = load_wfrag(src, 128, 16 * (f & 7), ll);
        *(bf16x8*)&Wl[f][ll][0] = fr;
    }
    __syncthreads();

    const int l = t & 63, q = l >> 4, e15 = l & 15;
    const int wv = blockIdx.x * 4 + (t >> 6), nw = gridDim.x * 4;
    const f32x4 z = {0.f, 0.f, 0.f, 0.f};

    const int nt = E >> 4;
    for (int tt = wv; tt < nt; tt += nw) {
        const int tb = tt * 16;
        const int e = tb + e15;
        const int i = eidx[e], j = eidx[E + e];
        const int d = off[i] + rank[e];
        const bf16x8 xj = *(const bf16x8*)&atomb[(size_t)j * 32 + 8 * q];
        const bf16x8 xe = *(const bf16x8*)&efb[(size_t)e * 32 + 8 * q];
        const float4 a4 = *(const float4*)&alpha[(size_t)e * 4];
        const float4 s4 = *(const float4*)&sbuf[(size_t)i * 4];
        float af[4];
#pragma unroll
        for (int h = 0; h < 4; ++h)
            af[h] = (&a4.x)[h] * __builtin_amdgcn_rcpf((&s4.x)[h] + 1e-16f);

        float c4[8] = {0,0,0,0,0,0,0,0};
#pragma unroll
        for (int mb = 0; mb < 8; ++mb) {
            const bf16x8 wa = *(const bf16x8*)&Wl[mb][l][0];
            const bf16x8 we = *(const bf16x8*)&Wl[8 + mb][l][0];
            const f32x4 ee = __builtin_amdgcn_mfma_f32_16x16x32_bf16(we, xe, z, 0, 0, 0);
            const f32x4 hb = __builtin_amdgcn_mfma_f32_16x16x32_bf16(wa, xj, z, 0, 0, 0);
            const float a = af[mb >> 1];
            const int s = (mb & 1) * 4;
#pragma unroll
            for (int r = 0; r < 4; ++r)
                c4[s + r] += spf(hb[r] + ee[r]) * a;
        }
#pragma unroll
        for (int s2 = 0; s2 < 2; ++s2) {
            short4 pk = { f2bf(c4[s2*4+0]), f2bf(c4[s2*4+1]), f2bf(c4[s2*4+2]), f2bf(c4[s2*4+3]) };
            *(short4*)&msg[(size_t)d * 32 + s2 * 16 + 4 * q] = pk;
        }
    }
}

// kred: per node, stream its sorted msg rows, x0.25, +bias -> outp (f32) + outb (bf16)
__global__ __launch_bounds__(256) void kred(
    const int* __restrict__ off, const short* __restrict__ msg, FP bias,
    float* __restrict__ outp, short* __restrict__ outb, int N)
{
    const int lane = threadIdx.x & 31;
    const int sub = threadIdx.x >> 5;
    const float b = bias[lane];
    for (int node = blockIdx.x * 8 + sub; node < N; node += gridDim.x * 8) {
        const int o0 = off[node], o1 = off[node + 1];
        float acc = 0.f;
        for (int p = o0; p < o1; ++p) acc += bf2f(msg[(size_t)p * 32 + lane]);
        const float v = 0.25f * acc + b;
        outp[(size_t)node * 32 + lane] = v;
        outb[(size_t)node * 32 + lane] = f2bf(v);
    }
}

// ---------------------------------------------------------------------------
// kG2v: edge MLP. Interleaved silu->MFMA per kc slice (hs = 5.1 KB; LDS 38.5 KB
// -> 4 blocks/CU). (256,2): a1[8]+xb need ~88 VGPR (the (256,4) cap spilled).
// ---------------------------------------------------------------------------
__global__ __launch_bounds__(256, 2) void kG2v(
    const short* __restrict__ efb, const int* __restrict__ eidx,
    const short* __restrict__ outb,
    FP W1g, FP W2, FP b1g, FP b2g, float* __restrict__ eout, int E)
{
    __shared__ __align__(16) short W1f[3][8][64][8];   // 24 KB
    __shared__ __align__(16) short W2f[8][64][8];      // 8 KB
    __shared__ float b1l[128];
    __shared__ float b2l[32];
    __shared__ __align__(16) short hs[4][16 * 40];     // 5.1 KB: one kc slice/wave
    const int t = threadIdx.x;
    for (int s = t; s < 3 * 8 * 64; s += 256) {
        const int ks = s >> 9, rem = s & 511, mb = rem >> 6, ll = rem & 63;
        const int c = 16 * mb + (ll & 15);
        const int k0 = ks * 32 + 8 * (ll >> 4);
        bf16x8 f;
#pragma unroll
        for (int j = 0; j < 8; ++j) f[j] = f2bf(W1g[(size_t)(k0 + j) * 128 + c]);
        *(bf16x8*)&W1f[ks][mb][ll][0] = f;
    }
    for (int s = t; s < 8 * 64; s += 256) {
        const int f = s >> 6, ll = s & 63;
        const int kc = f >> 1, m2 = f & 1;
        bf16x8 fr = load_wfrag(W2 + 32 * kc * 32, 32, 16 * m2, ll);
        *(bf16x8*)&W2f[f][ll][0] = fr;
    }
    if (t < 128) b1l[t] = b1g[t];
    if (t < 32)  b2l[t] = b2g[t];
    __syncthreads();

    const int l = t & 63, q = l >> 4, e15 = l & 15, wvb = t >> 6;
    short* hw = &hs[wvb][0];
    const f32x4 z = {0.f, 0.f, 0.f, 0.f};

    const int wv = blockIdx.x * 4 + wvb, nw = gridDim.x * 4, nt = E >> 4;
    for (int tt = wv; tt < nt; tt += nw) {
        const int tb = tt * 16;
        const int e = tb + e15;
        const int ri = eidx[e], ci = eidx[E + e];
        bf16x8 xb[3];
        xb[0] = *(const bf16x8*)&outb[(size_t)ri * 32 + 8 * q];
        xb[1] = *(const bf16x8*)&outb[(size_t)ci * 32 + 8 * q];
        xb[2] = *(const bf16x8*)&efb[(size_t)e * 32 + 8 * q];

        f32x4 a1[8] = {z, z, z, z, z, z, z, z};
#pragma unroll
        for (int ks = 0; ks < 3; ++ks)
#pragma unroll
            for (int mb = 0; mb < 8; ++mb) {
                const bf16x8 wfr = *(const bf16x8*)&W1f[ks][mb][l][0];
                a1[mb] = __builtin_amdgcn_mfma_f32_16x16x32_bf16(wfr, xb[ks], a1[mb], 0, 0, 0);
            }
        f32x4 oc0 = z, oc1 = z;
#pragma unroll
        for (int kc = 0; kc < 4; ++kc) {
#pragma unroll
            for (int half = 0; half < 2; ++half) {
                const int mb = 2 * kc + half;
                short4 s;
                s.x = f2bf(silu_f(a1[mb][0] + b1l[16 * mb + 4 * q + 0]));
                s.y = f2bf(silu_f(a1[mb][1] + b1l[16 * mb + 4 * q + 1]));
                s.z = f2bf(silu_f(a1[mb][2] + b1l[16 * mb + 4 * q + 2]));
                s.w = f2bf(silu_f(a1[mb][3] + b1l[16 * mb + 4 * q + 3]));
                *(short4*)&hw[e15 * 40 + half * 16 + 4 * q] = s;   // wave-internal, in-order DS
            }
            const bf16x8 hf = *(const bf16x8*)&hw[e15 * 40 + 8 * q];
            const bf16x8 w20 = *(const bf16x8*)&W2f[kc * 2][l][0];
            const bf16x8 w21 = *(const bf16x8*)&W2f[kc * 2 + 1][l][0];
            oc0 = __builtin_amdgcn_mfma_f32_16x16x32_bf16(w20, hf, oc0, 0, 0, 0);
            oc1 = __builtin_amdgcn_mfma_f32_16x16x32_bf16(w21, hf, oc1, 0, 0, 0);
        }
        float4 o0, o1;
#pragma unroll
        for (int r = 0; r < 4; ++r) {
            (&o0.x)[r] = silu_f(oc0[r] + b2l[4 * q + r]);
            (&o1.x)[r] = silu_f(oc1[r] + b2l[16 + 4 * q + r]);
        }
        *(float4*)&eout[(size_t)e * 32 + 4 * q] = o0;
        *(float4*)&eout[(size_t)e * 32 + 16 + 4 * q] = o1;
    }
}

extern "C" void kernel_launch(void* const* d_in, const int* in_sizes, int n_in,
                              void* d_out, int out_size, void* d_ws, size_t ws_size,
                              hipStream_t stream)
{
    const float* atom = (const float*)d_in[0];
    const int*   eidx = (const int*)d_in[1];
    const float* efea = (const float*)d_in[2];
    const float* Wg   = (const float*)d_in[6];
    const float* attg = (const float*)d_in[7];
    const float* bias = (const float*)d_in[8];
    const float* gam  = (const float*)d_in[9];
    const float* bet  = (const float*)d_in[10];
    const float* W1g  = (const float*)d_in[11];
    const float* b1g  = (const float*)d_in[12];
    const float* W2g  = (const float*)d_in[13];
    const float* b2g  = (const float*)d_in[14];

    const int N = in_sizes[0] / 32;
    const int E = in_sizes[2] / 32;
    const int NBLK = 4096;
    const int nbs = (N + 255) >> 8;               // scan blocks

    // workspace layout (f32 units, 16B-aligned sections)
    float* ws = (float*)d_ws;
    size_t o = 0;
    float* sbuf   = ws + o;          o += (size_t)4 * N;   // zeroed
    int*   cnt    = (int*)(ws + o);  o += N;               // zeroed
    float* bnsc   = ws + o;          o += 8;
    int*   off    = (int*)(ws + o);  o += (size_t)N + 1;
    o = (o + 3) & ~(size_t)3;
    int*   rank   = (int*)(ws + o);  o += E;
    int*   part   = (int*)(ws + o);  o += (size_t)nbs + 4;
    o = (o + 3) & ~(size_t)3;
    float* bnpart = ws + o;          o += (size_t)NBLK * 16;
    o = (o + 7) & ~(size_t)7;
    short* atomb  = (short*)(ws + o); o += (size_t)N * 16;   // N*32 bf16
    short* efb    = (short*)(ws + o); o += (size_t)E * 16;   // E*32 bf16
    short* outb   = (short*)(ws + o); o += (size_t)N * 16;   // N*32 bf16

    // d_out: [out N*32 f32][eout E*32 f32]; eout region = alpha + msg scratch
    float* outp  = (float*)d_out;
    float* scratch = outp + (size_t)N * 32;
    float* alpha = scratch;                          // 4E f32
    short* msg   = (short*)(scratch + (size_t)4 * E);// E*32 bf16 (sorted messages)
    float* eout  = scratch;                          // written last by kG2v

    hipMemsetAsync(ws, 0, (size_t)5 * N * sizeof(float), stream);  // sbuf,cnt

    const int n4e = 4 * E;
    kprep<<<2048, 256, 0, stream>>>(atom, efea, eidx, atomb, efb, cnt, rank, N * 8, E * 8, E);
    kscanA<<<nbs, 256, 0, stream>>>(cnt, part, N);
    kscanB<<<1, 1024, 0, stream>>>(part, nbs);
    kscanC<<<nbs, 256, 0, stream>>>(cnt, part, off, N);
    kBc  <<<NBLK, 256, 0, stream>>>(efb, eidx, atomb, Wg, attg, alpha, bnpart, E);
    k2_bn<<<1, 256, 0, stream>>>(bnpart, NBLK, gam, bet, bnsc, E);
    k34  <<<(n4e + 255) / 256, 256, 0, stream>>>(alpha, eidx, sbuf, bnsc, E);
    kmsg3<<<4096, 256, 0, stream>>>(efb, eidx, atomb, off, rank, Wg, alpha, sbuf, msg, E);
    kred <<<4096, 256, 0, stream>>>(off, msg, bias, outp, outb, N);
    kG2v <<<2048, 256, 0, stream>>>(efb, eidx, outb, W1g, W2g, b1g, b2g, eout, E);
}

// Round 18
// 367.463 us; speedup vs baseline: 1.1926x; 1.0168x over previous
//
#include <hip/hip_runtime.h>

typedef __attribute__((ext_vector_type(8))) short bf16x8;
typedef __attribute__((ext_vector_type(4))) float f32x4;

#define FP const float* __restrict__

__device__ __forceinline__ short f2bf(float f) {
    unsigned u = __float_as_uint(f);
    u += 0x7fffu + ((u >> 16) & 1u);
    return (short)(u >> 16);
}
__device__ __forceinline__ float bf2f(short s) {
    return __uint_as_float(((unsigned)(unsigned short)s) << 16);
}
__device__ __forceinline__ float v_exp2(float x) { float r; asm("v_exp_f32 %0, %1" : "=v"(r) : "v"(x)); return r; }
__device__ __forceinline__ float v_log2(float x) { float r; asm("v_log_f32 %0, %1" : "=v"(r) : "v"(x)); return r; }

__device__ __forceinline__ float fexp(float x) { return v_exp2(1.44269504f * x); }
__device__ __forceinline__ float sp(float x) {         // exact softplus (BN/softmax path)
    return fmaxf(x, 0.f) + 0.69314718f * v_log2(1.f + v_exp2(-1.44269504f * fabsf(x)));
}
// fast softplus: cubic fit of log2(1+t), abs err ~1e-3 (<< bf16 rounding).
__device__ __forceinline__ float spf(float x) {
    const float t = v_exp2(-1.44269504f * fabsf(x));
    const float p = t * (1.419f + t * (-0.573f + 0.154f * t));
    return fmaxf(x, 0.f) + 0.69314718f * p;
}
__device__ __forceinline__ float silu_f(float x) {
    return x * __builtin_amdgcn_rcpf(1.f + v_exp2(-1.44269504f * x));
}

// A-operand = W^T tile: lane l holds W[k, c0+(l&15)], k = 8*(l>>4)+j. W is [32+,ld] f32.
__device__ __forceinline__ bf16x8 load_wfrag(FP w, int ld, int c0, int l) {
    const int c = c0 + (l & 15);
    const int k0 = 8 * (l >> 4);
    bf16x8 f;
#pragma unroll
    for (int j = 0; j < 8; ++j) f[j] = f2bf(w[(k0 + j) * ld + c]);
    return f;
}

// ---------------------------------------------------------------------------
// kprep: bf16-ize atom (N*32) and ef (E*32) + in-degree histogram/rank (merged)
// ---------------------------------------------------------------------------
__global__ __launch_bounds__(256) void kprep(
    FP atom, FP ef, const int* __restrict__ eidx,
    short* __restrict__ atomb, short* __restrict__ efb,
    int* __restrict__ cnt, int* __restrict__ rank,
    int nA4, int nE4, int E)
{
    const int stride = gridDim.x * 256;
    const int tot = nA4 + nE4 + E;
    for (int t = blockIdx.x * 256 + threadIdx.x; t < tot; t += stride) {
        if (t < nA4) {
            const float4 v = ((const float4*)atom)[t];
            short4 s = { f2bf(v.x), f2bf(v.y), f2bf(v.z), f2bf(v.w) };
            ((short4*)atomb)[t] = s;
        } else if (t < nA4 + nE4) {
            const float4 v = ((const float4*)ef)[t - nA4];
            short4 s = { f2bf(v.x), f2bf(v.y), f2bf(v.z), f2bf(v.w) };
            ((short4*)efb)[t - nA4] = s;
        } else {
            const int e = t - nA4 - nE4;
            rank[e] = atomicAdd(&cnt[eidx[e]], 1);
        }
    }
}

// kscanA: per-block sum of cnt -> part[b]
__global__ __launch_bounds__(256) void kscanA(
    const int* __restrict__ cnt, int* __restrict__ part, int N)
{
    __shared__ int wsum[4];
    const int t = threadIdx.x;
    const int i = blockIdx.x * 256 + t;
    int v = (i < N) ? cnt[i] : 0;
#pragma unroll
    for (int d = 1; d < 64; d <<= 1) v += __shfl_xor(v, d);
    if ((t & 63) == 0) wsum[t >> 6] = v;
    __syncthreads();
    if (t == 0) part[blockIdx.x] = wsum[0] + wsum[1] + wsum[2] + wsum[3];
}

// kscanB: single block exclusive scan over nb partials (nb <= 1024)
__global__ __launch_bounds__(1024) void kscanB(
    int* __restrict__ part, int nb)
{
    __shared__ int pa[1024], pb[1024];
    const int t = threadIdx.x;
    pa[t] = (t < nb) ? part[t] : 0;
    __syncthreads();
    int* src = pa; int* dst = pb;
#pragma unroll
    for (int d = 1; d < 1024; d <<= 1) {
        int v = src[t];
        if (t >= d) v += src[t - d];
        dst[t] = v;
        __syncthreads();
        int* tmp = src; src = dst; dst = tmp;
    }
    if (t < nb) part[t] = (t == 0) ? 0 : src[t - 1];
}

// kscanC: block-local scan + base -> off[i]; last element writes off[N]
__global__ __launch_bounds__(256) void kscanC(
    const int* __restrict__ cnt, const int* __restrict__ part,
    int* __restrict__ off, int N)
{
    __shared__ int pa[256], pb[256];
    const int t = threadIdx.x;
    const int i = blockIdx.x * 256 + t;
    const int c = (i < N) ? cnt[i] : 0;
    pa[t] = c;
    __syncthreads();
    int* src = pa; int* dst = pb;
#pragma unroll
    for (int d = 1; d < 256; d <<= 1) {
        int v = src[t];
        if (t >= d) v += src[t - d];
        dst[t] = v;
        __syncthreads();
        int* tmp = src; src = dst; dst = tmp;
    }
    const int incl = src[t];
    const int base = part[blockIdx.x];
    if (i < N) off[i] = base + incl - c;
    if (i == N - 1) off[N] = base + incl;
}

// ---------------------------------------------------------------------------
// kBc: 1-deep software pipeline: tile t+1's eidx+row gathers issue before
// tile t's MFMA/softplus body (wave-uniform prefetch branch). Weights in LDS.
// ---------------------------------------------------------------------------
__global__ __launch_bounds__(256, 4) void kBc(
    const short* __restrict__ efb, const int* __restrict__ eidx,
    const short* __restrict__ atomb, FP Wg, FP attg,
    float* __restrict__ alpha, float* __restrict__ bnpart, int E)
{
    __shared__ float attl[256];
    __shared__ __align__(16) short Wl[16][64][8];   // 16 KB
    __shared__ float bnred[4][8];
    const int t = threadIdx.x;
    if (t < 64) ((float4*)attl)[t] = ((const float4*)attg)[t];
    for (int s = t; s < 1024; s += 256) {
        const int f = s >> 6, ll = s & 63;
        FP src = (f < 8) ? Wg : (Wg + 32 * 128);
        bf16x8 fr = load_wfrag(src, 128, 16 * (f & 7), ll);
        *(bf16x8*)&Wl[f][ll][0] = fr;
    }
    __syncthreads();

    const int l = t & 63, q = l >> 4, e15 = l & 15, wvb = t >> 6;
    const int wv = blockIdx.x * 4 + wvb, nw = gridDim.x * 4;
    const f32x4 z = {0.f, 0.f, 0.f, 0.f};
    float bs[4] = {0,0,0,0}, bq2[4] = {0,0,0,0};

    const int nt = E >> 4;
    int tt = wv;
    bf16x8 xi_c, xj_c, xe_c;
    if (tt < nt) {
        const int e = tt * 16 + e15;
        const int i = eidx[e], j = eidx[E + e];
        xi_c = *(const bf16x8*)&atomb[(size_t)i * 32 + 8 * q];
        xj_c = *(const bf16x8*)&atomb[(size_t)j * 32 + 8 * q];
        xe_c = *(const bf16x8*)&efb[(size_t)e * 32 + 8 * q];
    }
    while (tt < nt) {
        const int ttn = tt + nw;
        bf16x8 xi_n, xj_n, xe_n;
        if (ttn < nt) {   // wave-uniform prefetch of next tile
            const int en = ttn * 16 + e15;
            const int in_ = eidx[en], jn = eidx[E + en];
            xi_n = *(const bf16x8*)&atomb[(size_t)in_ * 32 + 8 * q];
            xj_n = *(const bf16x8*)&atomb[(size_t)jn * 32 + 8 * q];
            xe_n = *(const bf16x8*)&efb[(size_t)en * 32 + 8 * q];
        }
        const int e = tt * 16 + e15;
        float ph[4] = {0,0,0,0};
#pragma unroll
        for (int mb = 0; mb < 8; ++mb) {
            const bf16x8 wa = *(const bf16x8*)&Wl[mb][l][0];
            const bf16x8 we = *(const bf16x8*)&Wl[8 + mb][l][0];
            const f32x4 ee = __builtin_amdgcn_mfma_f32_16x16x32_bf16(we, xe_c, z, 0, 0, 0);
            const f32x4 ha = __builtin_amdgcn_mfma_f32_16x16x32_bf16(wa, xi_c, z, 0, 0, 0);
            const f32x4 hb = __builtin_amdgcn_mfma_f32_16x16x32_bf16(wa, xj_c, z, 0, 0, 0);
            const int h = mb >> 1;
            const int c0 = (mb & 1) * 16 + 4 * q;
#pragma unroll
            for (int r = 0; r < 4; ++r) {
                ph[h] += spf(ha[r] + ee[r]) * attl[h * 64 + c0 + r]
                       + spf(hb[r] + ee[r]) * attl[h * 64 + 32 + c0 + r];
            }
        }
        float4 a0v;
#pragma unroll
        for (int h = 0; h < 4; ++h) {
            float v = ph[h];
            v += __shfl_xor(v, 16);
            v += __shfl_xor(v, 32);
            (&a0v.x)[h] = sp(v);
        }
        if (q == 0) {
            *(float4*)&alpha[(size_t)e * 4] = a0v;
#pragma unroll
            for (int h = 0; h < 4; ++h) {
                const float a0 = (&a0v.x)[h];
                bs[h] += a0; bq2[h] += a0 * a0;
            }
        }
        tt = ttn;
        xi_c = xi_n; xj_c = xj_n; xe_c = xe_n;
    }
#pragma unroll
    for (int h = 0; h < 4; ++h) {
        float v = bs[h], w = bq2[h];
#pragma unroll
        for (int d = 1; d < 64; d <<= 1) { v += __shfl_xor(v, d); w += __shfl_xor(w, d); }
        if (l == 0) { bnred[wvb][h] = v; bnred[wvb][4 + h] = w; }
    }
    __syncthreads();
    if (t < 8) {
        const float s = bnred[0][t] + bnred[1][t] + bnred[2][t] + bnred[3][t];
        bnpart[(size_t)blockIdx.x * 16 + t] = s;
    }
}

// k2: reduce per-block BN partials, finalize scale/shift
__global__ __launch_bounds__(256) void k2_bn(
    const float* __restrict__ bnpart, int nblk, FP gam, FP bet,
    float* __restrict__ bnsc, int E)
{
    __shared__ float red[256];
    const int t = threadIdx.x;
    const int h = t & 7, c = t >> 3;
    float s = 0.f;
    for (int b = c; b < nblk; b += 32) s += bnpart[(size_t)b * 16 + h];
    red[t] = s;
    __syncthreads();
    if (t < 8) {
        float acc = 0.f;
#pragma unroll
        for (int c2 = 0; c2 < 32; ++c2) acc += red[c2 * 8 + t];
        red[t] = acc;
    }
    __syncthreads();
    if (t < 4) {
        const float inv = 1.f / (float)E;
        const float mu  = red[t] * inv;
        const float var = red[4 + t] * inv - mu * mu;
        const float scl = gam[t] * rsqrtf(var + 1e-5f);
        bnsc[t] = scl;
        bnsc[4 + t] = bet[t] - mu * scl;
    }
}

// k34: alpha -> ex = exp(sp(scale*alpha+shift)) in place; distributed seg-sum.
__global__ __launch_bounds__(256) void k34(
    float* __restrict__ alpha, const int* __restrict__ eidx,
    float* __restrict__ sbuf, const float* __restrict__ bnsc, int E)
{
    const int t = blockIdx.x * 256 + threadIdx.x;
    if (t >= 4 * E) return;
    const int e = t >> 2, h = t & 3;
    const float a1 = sp(bnsc[h] * alpha[t] + bnsc[4 + h]);
    const float ex = fexp(a1);
    alpha[t] = ex;
    atomicAdd(&sbuf[eidx[e] * 4 + h], ex);
}

// ---------------------------------------------------------------------------
// kmsg3: 1-deep software pipeline (prefetch next tile's indices, rows, alpha,
// sbuf, dst); plain scatter store, NO atomics.
// ---------------------------------------------------------------------------
__global__ __launch_bounds__(256, 4) void kmsg3(
    const short* __restrict__ efb, const int* __restrict__ eidx,
    const short* __restrict__ atomb, const int* __restrict__ off,
    const int* __restrict__ rank, FP Wg,
    const float* __restrict__ alpha, const float* __restrict__ sbuf,
    short* __restrict__ msg, int E)
{
    __shared__ __align__(16) short Wl[16][64][8];   // 16 KB
    const int t = threadIdx.x;
    for (int s = t; s < 1024; s += 256) {
        const int f = s >> 6, ll = s & 63;
        FP src = (f < 8) ? Wg : (Wg + 32 * 128);
        bf16x8 fr = load_wfrag(src, 128, 16 * (f & 7), ll);
        *(bf16x8*)&Wl[f][ll][0] = fr;
    }
    __syncthreads();

    const int l = t & 63, q = l >> 4, e15 = l & 15;
    const int wv = blockIdx.x * 4 + (t >> 6), nw = gridDim.x * 4;
    const f32x4 z = {0.f, 0.f, 0.f, 0.f};

    const int nt = E >> 4;
    int tt = wv;
    bf16x8 xj_c, xe_c;
    float4 a4_c, s4_c;
    int d_c = 0;
    if (tt < nt) {
        const int e = tt * 16 + e15;
        const int i = eidx[e], j = eidx[E + e];
        d_c = off[i] + rank[e];
        xj_c = *(const bf16x8*)&atomb[(size_t)j * 32 + 8 * q];
        xe_c = *(const bf16x8*)&efb[(size_t)e * 32 + 8 * q];
        a4_c = *(const float4*)&alpha[(size_t)e * 4];
        s4_c = *(const float4*)&sbuf[(size_t)i * 4];
    }
    while (tt < nt) {
        const int ttn = tt + nw;
        bf16x8 xj_n, xe_n;
        float4 a4_n, s4_n;
        int d_n = 0;
        if (ttn < nt) {   // wave-uniform prefetch
            const int en = ttn * 16 + e15;
            const int in_ = eidx[en], jn = eidx[E + en];
            d_n = off[in_] + rank[en];
            xj_n = *(const bf16x8*)&atomb[(size_t)jn * 32 + 8 * q];
            xe_n = *(const bf16x8*)&efb[(size_t)en * 32 + 8 * q];
            a4_n = *(const float4*)&alpha[(size_t)en * 4];
            s4_n = *(const float4*)&sbuf[(size_t)in_ * 4];
        }
        float af[4];
#pragma unroll
        for (int h = 0; h < 4; ++h)
            af[h] = (&a4_c.x)[h] * __builtin_amdgcn_rcpf((&s4_c.x)[h] + 1e-16f);

        float c4[8] = {0,0,0,0,0,0,0,0};
#pragma unroll
        for (int mb = 0; mb < 8; ++mb) {
            const bf16x8 wa = *(const bf16x8*)&Wl[mb][l][0];
            const bf16x8 we = *(const bf16x8*)&Wl[8 + mb][l][0];
            const f32x4 ee = __builtin_amdgcn_mfma_f32_16x16x32_bf16(we, xe_c, z, 0, 0, 0);
            const f32x4 hb = __builtin_amdgcn_mfma_f32_16x16x32_bf16(wa, xj_c, z, 0, 0, 0);
            const float a = af[mb >> 1];
            const int s = (mb & 1) * 4;
#pragma unroll
            for (int r = 0; r < 4; ++r)
                c4[s + r] += spf(hb[r] + ee[r]) * a;
        }
#pragma unroll
        for (int s2 = 0; s2 < 2; ++s2) {
            short4 pk = { f2bf(c4[s2*4+0]), f2bf(c4[s2*4+1]), f2bf(c4[s2*4+2]), f2bf(c4[s2*4+3]) };
            *(short4*)&msg[(size_t)d_c * 32 + s2 * 16 + 4 * q] = pk;
        }
        tt = ttn;
        d_c = d_n; xj_c = xj_n; xe_c = xe_n; a4_c = a4_n; s4_c = s4_n;
    }
}

// kred: per node, stream its sorted msg rows, x0.25, +bias -> outp (f32) + outb (bf16)
__global__ __launch_bounds__(256) void kred(
    const int* __restrict__ off, const short* __restrict__ msg, FP bias,
    float* __restrict__ outp, short* __restrict__ outb, int N)
{
    const int lane = threadIdx.x & 31;
    const int sub = threadIdx.x >> 5;
    const float b = bias[lane];
    for (int node = blockIdx.x * 8 + sub; node < N; node += gridDim.x * 8) {
        const int o0 = off[node], o1 = off[node + 1];
        float acc = 0.f;
        for (int p = o0; p < o1; ++p) acc += bf2f(msg[(size_t)p * 32 + lane]);
        const float v = 0.25f * acc + b;
        outp[(size_t)node * 32 + lane] = v;
        outb[(size_t)node * 32 + lane] = f2bf(v);
    }
}

// ---------------------------------------------------------------------------
// kG2v: edge MLP with 1-deep pipeline on the outb/efb gathers. Interleaved
// silu->MFMA per kc slice (hs 5.1 KB; LDS 38.5 KB -> 4 blocks/CU). (256,2).
// ---------------------------------------------------------------------------
__global__ __launch_bounds__(256, 2) void kG2v(
    const short* __restrict__ efb, const int* __restrict__ eidx,
    const short* __restrict__ outb,
    FP W1g, FP W2, FP b1g, FP b2g, float* __restrict__ eout, int E)
{
    __shared__ __align__(16) short W1f[3][8][64][8];   // 24 KB
    __shared__ __align__(16) short W2f[8][64][8];      // 8 KB
    __shared__ float b1l[128];
    __shared__ float b2l[32];
    __shared__ __align__(16) short hs[4][16 * 40];     // 5.1 KB: one kc slice/wave
    const int t = threadIdx.x;
    for (int s = t; s < 3 * 8 * 64; s += 256) {
        const int ks = s >> 9, rem = s & 511, mb = rem >> 6, ll = rem & 63;
        const int c = 16 * mb + (ll & 15);
        const int k0 = ks * 32 + 8 * (ll >> 4);
        bf16x8 f;
#pragma unroll
        for (int j = 0; j < 8; ++j) f[j] = f2bf(W1g[(size_t)(k0 + j) * 128 + c]);
        *(bf16x8*)&W1f[ks][mb][ll][0] = f;
    }
    for (int s = t; s < 8 * 64; s += 256) {
        const int f = s >> 6, ll = s & 63;
        const int kc = f >> 1, m2 = f & 1;
        bf16x8 fr = load_wfrag(W2 + 32 * kc * 32, 32, 16 * m2, ll);
        *(bf16x8*)&W2f[f][ll][0] = fr;
    }
    if (t < 128) b1l[t] = b1g[t];
    if (t < 32)  b2l[t] = b2g[t];
    __syncthreads();

    const int l = t & 63, q = l >> 4, e15 = l & 15, wvb = t >> 6;
    short* hw = &hs[wvb][0];
    const f32x4 z = {0.f, 0.f, 0.f, 0.f};

    const int wv = blockIdx.x * 4 + wvb, nw = gridDim.x * 4, nt = E >> 4;
    int tt = wv;
    bf16x8 xb0_c, xb1_c, xb2_c;
    if (tt < nt) {
        const int e = tt * 16 + e15;
        const int ri = eidx[e], ci = eidx[E + e];
        xb0_c = *(const bf16x8*)&outb[(size_t)ri * 32 + 8 * q];
        xb1_c = *(const bf16x8*)&outb[(size_t)ci * 32 + 8 * q];
        xb2_c = *(const bf16x8*)&efb[(size_t)e * 32 + 8 * q];
    }
    while (tt < nt) {
        const int ttn = tt + nw;
        bf16x8 xb0_n, xb1_n, xb2_n;
        if (ttn < nt) {   // wave-uniform prefetch
            const int en = ttn * 16 + e15;
            const int rn = eidx[en], cn = eidx[E + en];
            xb0_n = *(const bf16x8*)&outb[(size_t)rn * 32 + 8 * q];
            xb1_n = *(const bf16x8*)&outb[(size_t)cn * 32 + 8 * q];
            xb2_n = *(const bf16x8*)&efb[(size_t)en * 32 + 8 * q];
        }
        const int e = tt * 16 + e15;
        f32x4 a1[8] = {z, z, z, z, z, z, z, z};
#pragma unroll
        for (int mb = 0; mb < 8; ++mb) {
            a1[mb] = __builtin_amdgcn_mfma_f32_16x16x32_bf16(*(const bf16x8*)&W1f[0][mb][l][0], xb0_c, a1[mb], 0, 0, 0);
            a1[mb] = __builtin_amdgcn_mfma_f32_16x16x32_bf16(*(const bf16x8*)&W1f[1][mb][l][0], xb1_c, a1[mb], 0, 0, 0);
            a1[mb] = __builtin_amdgcn_mfma_f32_16x16x32_bf16(*(const bf16x8*)&W1f[2][mb][l][0], xb2_c, a1[mb], 0, 0, 0);
        }
        f32x4 oc0 = z, oc1 = z;
#pragma unroll
        for (int kc = 0; kc < 4; ++kc) {
#pragma unroll
            for (int half = 0; half < 2; ++half) {
                const int mb = 2 * kc + half;
                short4 s;
                s.x = f2bf(silu_f(a1[mb][0] + b1l[16 * mb + 4 * q + 0]));
                s.y = f2bf(silu_f(a1[mb][1] + b1l[16 * mb + 4 * q + 1]));
                s.z = f2bf(silu_f(a1[mb][2] + b1l[16 * mb + 4 * q + 2]));
                s.w = f2bf(silu_f(a1[mb][3] + b1l[16 * mb + 4 * q + 3]));
                *(short4*)&hw[e15 * 40 + half * 16 + 4 * q] = s;   // wave-internal, in-order DS
            }
            const bf16x8 hf = *(const bf16x8*)&hw[e15 * 40 + 8 * q];
            const bf16x8 w20 = *(const bf16x8*)&W2f[kc * 2][l][0];
            const bf16x8 w21 = *(const bf16x8*)&W2f[kc * 2 + 1][l][0];
            oc0 = __builtin_amdgcn_mfma_f32_16x16x32_bf16(w20, hf, oc0, 0, 0, 0);
            oc1 = __builtin_amdgcn_mfma_f32_16x16x32_bf16(w21, hf, oc1, 0, 0, 0);
        }
        float4 o0, o1;
#pragma unroll
        for (int r = 0; r < 4; ++r) {
            (&o0.x)[r] = silu_f(oc0[r] + b2l[4 * q + r]);
            (&o1.x)[r] = silu_f(oc1[r] + b2l[16 + 4 * q + r]);
        }
        *(float4*)&eout[(size_t)e * 32 + 4 * q] = o0;
        *(float4*)&eout[(size_t)e * 32 + 16 + 4 * q] = o1;
        tt = ttn;
        xb0_c = xb0_n; xb1_c = xb1_n; xb2_c = xb2_n;
    }
}

extern "C" void kernel_launch(void* const* d_in, const int* in_sizes, int n_in,
                              void* d_out, int out_size, void* d_ws, size_t ws_size,
                              hipStream_t stream)
{
    const float* atom = (const float*)d_in[0];
    const int*   eidx = (const int*)d_in[1];
    const float* efea = (const float*)d_in[2];
    const float* Wg   = (const float*)d_in[6];
    const float* attg = (const float*)d_in[7];
    const float* bias = (const float*)d_in[8];
    const float* gam  = (const float*)d_in[9];
    const float* bet  = (const float*)d_in[10];
    const float* W1g  = (const float*)d_in[11];
    const float* b1g  = (const float*)d_in[12];
    const float* W2g  = (const float*)d_in[13];
    const float* b2g  = (const float*)d_in[14];

    const int N = in_sizes[0] / 32;
    const int E = in_sizes[2] / 32;
    const int NBLK = 4096;
    const int nbs = (N + 255) >> 8;               // scan blocks

    // workspace layout (f32 units, 16B-aligned sections)
    float* ws = (float*)d_ws;
    size_t o = 0;
    float* sbuf   = ws + o;          o += (size_t)4 * N;   // zeroed
    int*   cnt    = (int*)(ws + o);  o += N;               // zeroed
    float* bnsc   = ws + o;          o += 8;
    int*   off    = (int*)(ws + o);  o += (size_t)N + 1;
    o = (o + 3) & ~(size_t)3;
    int*   rank   = (int*)(ws + o);  o += E;
    int*   part   = (int*)(ws + o);  o += (size_t)nbs + 4;
    o = (o + 3) & ~(size_t)3;
    float* bnpart = ws + o;          o += (size_t)NBLK * 16;
    o = (o + 7) & ~(size_t)7;
    short* atomb  = (short*)(ws + o); o += (size_t)N * 16;   // N*32 bf16
    short* efb    = (short*)(ws + o); o += (size_t)E * 16;   // E*32 bf16
    short* outb   = (short*)(ws + o); o += (size_t)N * 16;   // N*32 bf16

    // d_out: [out N*32 f32][eout E*32 f32]; eout region = alpha + msg scratch
    float* outp  = (float*)d_out;
    float* scratch = outp + (size_t)N * 32;
    float* alpha = scratch;                          // 4E f32
    short* msg   = (short*)(scratch + (size_t)4 * E);// E*32 bf16 (sorted messages)
    float* eout  = scratch;                          // written last by kG2v

    hipMemsetAsync(ws, 0, (size_t)5 * N * sizeof(float), stream);  // sbuf,cnt

    const int n4e = 4 * E;
    kprep<<<2048, 256, 0, stream>>>(atom, efea, eidx, atomb, efb, cnt, rank, N * 8, E * 8, E);
    kscanA<<<nbs, 256, 0, stream>>>(cnt, part, N);
    kscanB<<<1, 1024, 0, stream>>>(part, nbs);
    kscanC<<<nbs, 256, 0, stream>>>(cnt, part, off, N);
    kBc  <<<NBLK, 256, 0, stream>>>(efb, eidx, atomb, Wg, attg, alpha, bnpart, E);
    k2_bn<<<1, 256, 0, stream>>>(bnpart, NBLK, gam, bet, bnsc, E);
    k34  <<<(n4e + 255) / 256, 256, 0, stream>>>(alpha, eidx, sbuf, bnsc, E);
    kmsg3<<<4096, 256, 0, stream>>>(efb, eidx, atomb, off, rank, Wg, alpha, sbuf, msg, E);
    kred <<<4096, 256, 0, stream>>>(off, msg, bias, outp, outb, N);
    kG2v <<<2048, 256, 0, stream>>>(efb, eidx, outb, W1g, W2g, b1g, b2g, eout, E);
}

// Round 19
// 364.936 us; speedup vs baseline: 1.2008x; 1.0069x over previous
//
#include <hip/hip_runtime.h>

typedef __attribute__((ext_vector_type(8))) short bf16x8;
typedef __attribute__((ext_vector_type(4))) float f32x4;

#define FP const float* __restrict__

__device__ __forceinline__ short f2bf(float f) {
    unsigned u = __float_as_uint(f);
    u += 0x7fffu + ((u >> 16) & 1u);
    return (short)(u >> 16);
}
__device__ __forceinline__ float bf2f(short s) {
    return __uint_as_float(((unsigned)(unsigned short)s) << 16);
}
__device__ __forceinline__ float v_exp2(float x) { float r; asm("v_exp_f32 %0, %1" : "=v"(r) : "v"(x)); return r; }
__device__ __forceinline__ float v_log2(float x) { float r; asm("v_log_f32 %0, %1" : "=v"(r) : "v"(x)); return r; }

__device__ __forceinline__ float fexp(float x) { return v_exp2(1.44269504f * x); }
__device__ __forceinline__ float sp(float x) {         // exact softplus (BN/softmax path)
    return fmaxf(x, 0.f) + 0.69314718f * v_log2(1.f + v_exp2(-1.44269504f * fabsf(x)));
}
// fast softplus: cubic fit of log2(1+t), abs err ~1e-3 (<< bf16 rounding).
__device__ __forceinline__ float spf(float x) {
    const float t = v_exp2(-1.44269504f * fabsf(x));
    const float p = t * (1.419f + t * (-0.573f + 0.154f * t));
    return fmaxf(x, 0.f) + 0.69314718f * p;
}
__device__ __forceinline__ float silu_f(float x) {
    return x * __builtin_amdgcn_rcpf(1.f + v_exp2(-1.44269504f * x));
}

// A-operand = W^T tile: lane l holds W[k, c0+(l&15)], k = 8*(l>>4)+j. W is [32+,ld] f32.
__device__ __forceinline__ bf16x8 load_wfrag(FP w, int ld, int c0, int l) {
    const int c = c0 + (l & 15);
    const int k0 = 8 * (l >> 4);
    bf16x8 f;
#pragma unroll
    for (int j = 0; j < 8; ++j) f[j] = f2bf(w[(k0 + j) * ld + c]);
    return f;
}

// ---------------------------------------------------------------------------
// kprep: bf16-ize atom (N*32) and ef (E*32) + in-degree histogram/rank (merged)
// ---------------------------------------------------------------------------
__global__ __launch_bounds__(256) void kprep(
    FP atom, FP ef, const int* __restrict__ eidx,
    short* __restrict__ atomb, short* __restrict__ efb,
    int* __restrict__ cnt, int* __restrict__ rank,
    int nA4, int nE4, int E)
{
    const int stride = gridDim.x * 256;
    const int tot = nA4 + nE4 + E;
    for (int t = blockIdx.x * 256 + threadIdx.x; t < tot; t += stride) {
        if (t < nA4) {
            const float4 v = ((const float4*)atom)[t];
            short4 s = { f2bf(v.x), f2bf(v.y), f2bf(v.z), f2bf(v.w) };
            ((short4*)atomb)[t] = s;
        } else if (t < nA4 + nE4) {
            const float4 v = ((const float4*)ef)[t - nA4];
            short4 s = { f2bf(v.x), f2bf(v.y), f2bf(v.z), f2bf(v.w) };
            ((short4*)efb)[t - nA4] = s;
        } else {
            const int e = t - nA4 - nE4;
            rank[e] = atomicAdd(&cnt[eidx[e]], 1);
        }
    }
}

// kscanA: per-block sum of cnt -> part[b]
__global__ __launch_bounds__(256) void kscanA(
    const int* __restrict__ cnt, int* __restrict__ part, int N)
{
    __shared__ int wsum[4];
    const int t = threadIdx.x;
    const int i = blockIdx.x * 256 + t;
    int v = (i < N) ? cnt[i] : 0;
#pragma unroll
    for (int d = 1; d < 64; d <<= 1) v += __shfl_xor(v, d);
    if ((t & 63) == 0) wsum[t >> 6] = v;
    __syncthreads();
    if (t == 0) part[blockIdx.x] = wsum[0] + wsum[1] + wsum[2] + wsum[3];
}

// kscanB: single block exclusive scan over nb partials (nb <= 1024)
__global__ __launch_bounds__(1024) void kscanB(
    int* __restrict__ part, int nb)
{
    __shared__ int pa[1024], pb[1024];
    const int t = threadIdx.x;
    pa[t] = (t < nb) ? part[t] : 0;
    __syncthreads();
    int* src = pa; int* dst = pb;
#pragma unroll
    for (int d = 1; d < 1024; d <<= 1) {
        int v = src[t];
        if (t >= d) v += src[t - d];
        dst[t] = v;
        __syncthreads();
        int* tmp = src; src = dst; dst = tmp;
    }
    if (t < nb) part[t] = (t == 0) ? 0 : src[t - 1];
}

// kscanC: block-local scan + base -> off[i]; last element writes off[N]
__global__ __launch_bounds__(256) void kscanC(
    const int* __restrict__ cnt, const int* __restrict__ part,
    int* __restrict__ off, int N)
{
    __shared__ int pa[256], pb[256];
    const int t = threadIdx.x;
    const int i = blockIdx.x * 256 + t;
    const int c = (i < N) ? cnt[i] : 0;
    pa[t] = c;
    __syncthreads();
    int* src = pa; int* dst = pb;
#pragma unroll
    for (int d = 1; d < 256; d <<= 1) {
        int v = src[t];
        if (t >= d) v += src[t - d];
        dst[t] = v;
        __syncthreads();
        int* tmp = src; src = dst; dst = tmp;
    }
    const int incl = src[t];
    const int base = part[blockIdx.x];
    if (i < N) off[i] = base + incl - c;
    if (i == N - 1) off[N] = base + incl;
}

// ---------------------------------------------------------------------------
// kBc: single-tile, non-pipelined (R18's prefetch made it VALU-issue-bound at
// 87%); latency hidden by occupancy instead: (256,8) -> 8 blocks/CU
// (VGPR<=64 fits: R14's form was 60; LDS 17.9KB x 8 = 143KB <= 160KB).
// ---------------------------------------------------------------------------
__global__ __launch_bounds__(256, 8) void kBc(
    const short* __restrict__ efb, const int* __restrict__ eidx,
    const short* __restrict__ atomb, FP Wg, FP attg,
    float* __restrict__ alpha, float* __restrict__ bnpart, int E)
{
    __shared__ float attl[256];
    __shared__ __align__(16) short Wl[16][64][8];   // 16 KB
    __shared__ float bnred[4][8];
    const int t = threadIdx.x;
    if (t < 64) ((float4*)attl)[t] = ((const float4*)attg)[t];
    for (int s = t; s < 1024; s += 256) {
        const int f = s >> 6, ll = s & 63;
        FP src = (f < 8) ? Wg : (Wg + 32 * 128);
        bf16x8 fr = load_wfrag(src, 128, 16 * (f & 7), ll);
        *(bf16x8*)&Wl[f][ll][0] = fr;
    }
    __syncthreads();

    const int l = t & 63, q = l >> 4, e15 = l & 15, wvb = t >> 6;
    const int wv = blockIdx.x * 4 + wvb, nw = gridDim.x * 4;
    const f32x4 z = {0.f, 0.f, 0.f, 0.f};
    float bs[4] = {0,0,0,0}, bq2[4] = {0,0,0,0};

    const int nt = E >> 4;
    for (int tt = wv; tt < nt; tt += nw) {
        const int tb = tt * 16;
        const int e = tb + e15;
        const int i = eidx[e], j = eidx[E + e];
        const bf16x8 xi = *(const bf16x8*)&atomb[(size_t)i * 32 + 8 * q];
        const bf16x8 xj = *(const bf16x8*)&atomb[(size_t)j * 32 + 8 * q];
        const bf16x8 xe = *(const bf16x8*)&efb[(size_t)e * 32 + 8 * q];

        float ph[4] = {0,0,0,0};
#pragma unroll
        for (int mb = 0; mb < 8; ++mb) {
            const bf16x8 wa = *(const bf16x8*)&Wl[mb][l][0];
            const bf16x8 we = *(const bf16x8*)&Wl[8 + mb][l][0];
            const f32x4 ee = __builtin_amdgcn_mfma_f32_16x16x32_bf16(we, xe, z, 0, 0, 0);
            const f32x4 ha = __builtin_amdgcn_mfma_f32_16x16x32_bf16(wa, xi, z, 0, 0, 0);
            const f32x4 hb = __builtin_amdgcn_mfma_f32_16x16x32_bf16(wa, xj, z, 0, 0, 0);
            const int h = mb >> 1;
            const int c0 = (mb & 1) * 16 + 4 * q;
#pragma unroll
            for (int r = 0; r < 4; ++r) {
                ph[h] += spf(ha[r] + ee[r]) * attl[h * 64 + c0 + r]
                       + spf(hb[r] + ee[r]) * attl[h * 64 + 32 + c0 + r];
            }
        }
        float4 a0v;
#pragma unroll
        for (int h = 0; h < 4; ++h) {
            float v = ph[h];
            v += __shfl_xor(v, 16);
            v += __shfl_xor(v, 32);
            (&a0v.x)[h] = sp(v);
        }
        if (q == 0) {
            *(float4*)&alpha[(size_t)e * 4] = a0v;
#pragma unroll
            for (int h = 0; h < 4; ++h) {
                const float a0 = (&a0v.x)[h];
                bs[h] += a0; bq2[h] += a0 * a0;
            }
        }
    }
#pragma unroll
    for (int h = 0; h < 4; ++h) {
        float v = bs[h], w = bq2[h];
#pragma unroll
        for (int d = 1; d < 64; d <<= 1) { v += __shfl_xor(v, d); w += __shfl_xor(w, d); }
        if (l == 0) { bnred[wvb][h] = v; bnred[wvb][4 + h] = w; }
    }
    __syncthreads();
    if (t < 8) {
        const float s = bnred[0][t] + bnred[1][t] + bnred[2][t] + bnred[3][t];
        bnpart[(size_t)blockIdx.x * 16 + t] = s;
    }
}

// k2: reduce per-block BN partials, finalize scale/shift
__global__ __launch_bounds__(256) void k2_bn(
    const float* __restrict__ bnpart, int nblk, FP gam, FP bet,
    float* __restrict__ bnsc, int E)
{
    __shared__ float red[256];
    const int t = threadIdx.x;
    const int h = t & 7, c = t >> 3;
    float s = 0.f;
    for (int b = c; b < nblk; b += 32) s += bnpart[(size_t)b * 16 + h];
    red[t] = s;
    __syncthreads();
    if (t < 8) {
        float acc = 0.f;
#pragma unroll
        for (int c2 = 0; c2 < 32; ++c2) acc += red[c2 * 8 + t];
        red[t] = acc;
    }
    __syncthreads();
    if (t < 4) {
        const float inv = 1.f / (float)E;
        const float mu  = red[t] * inv;
        const float var = red[4 + t] * inv - mu * mu;
        const float scl = gam[t] * rsqrtf(var + 1e-5f);
        bnsc[t] = scl;
        bnsc[4 + t] = bet[t] - mu * scl;
    }
}

// k34: alpha -> ex = exp(sp(scale*alpha+shift)) in place; distributed seg-sum.
__global__ __launch_bounds__(256) void k34(
    float* __restrict__ alpha, const int* __restrict__ eidx,
    float* __restrict__ sbuf, const float* __restrict__ bnsc, int E)
{
    const int t = blockIdx.x * 256 + threadIdx.x;
    if (t >= 4 * E) return;
    const int e = t >> 2, h = t & 3;
    const float a1 = sp(bnsc[h] * alpha[t] + bnsc[4 + h]);
    const float ex = fexp(a1);
    alpha[t] = ex;
    atomicAdd(&sbuf[eidx[e] * 4 + h], ex);
}

// ---------------------------------------------------------------------------
// kmsg3: 1-deep software pipeline (kept: not VALU-saturated); scatter store.
// ---------------------------------------------------------------------------
__global__ __launch_bounds__(256, 4) void kmsg3(
    const short* __restrict__ efb, const int* __restrict__ eidx,
    const short* __restrict__ atomb, const int* __restrict__ off,
    const int* __restrict__ rank, FP Wg,
    const float* __restrict__ alpha, const float* __restrict__ sbuf,
    short* __restrict__ msg, int E)
{
    __shared__ __align__(16) short Wl[16][64][8];   // 16 KB
    const int t = threadIdx.x;
    for (int s = t; s < 1024; s += 256) {
        const int f = s >> 6, ll = s & 63;
        FP src = (f < 8) ? Wg : (Wg + 32 * 128);
        bf16x8 fr = load_wfrag(src, 128, 16 * (f & 7), ll);
        *(bf16x8*)&Wl[f][ll][0] = fr;
    }
    __syncthreads();

    const int l = t & 63, q = l >> 4, e15 = l & 15;
    const int wv = blockIdx.x * 4 + (t >> 6), nw = gridDim.x * 4;
    const f32x4 z = {0.f, 0.f, 0.f, 0.f};

    const int nt = E >> 4;
    int tt = wv;
    bf16x8 xj_c, xe_c;
    float4 a4_c, s4_c;
    int d_c = 0;
    if (tt < nt) {
        const int e = tt * 16 + e15;
        const int i = eidx[e], j = eidx[E + e];
        d_c = off[i] + rank[e];
        xj_c = *(const bf16x8*)&atomb[(size_t)j * 32 + 8 * q];
        xe_c = *(const bf16x8*)&efb[(size_t)e * 32 + 8 * q];
        a4_c = *(const float4*)&alpha[(size_t)e * 4];
        s4_c = *(const float4*)&sbuf[(size_t)i * 4];
    }
    while (tt < nt) {
        const int ttn = tt + nw;
        bf16x8 xj_n, xe_n;
        float4 a4_n, s4_n;
        int d_n = 0;
        if (ttn < nt) {   // wave-uniform prefetch
            const int en = ttn * 16 + e15;
            const int in_ = eidx[en], jn = eidx[E + en];
            d_n = off[in_] + rank[en];
            xj_n = *(const bf16x8*)&atomb[(size_t)jn * 32 + 8 * q];
            xe_n = *(const bf16x8*)&efb[(size_t)en * 32 + 8 * q];
            a4_n = *(const float4*)&alpha[(size_t)en * 4];
            s4_n = *(const float4*)&sbuf[(size_t)in_ * 4];
        }
        float af[4];
#pragma unroll
        for (int h = 0; h < 4; ++h)
            af[h] = (&a4_c.x)[h] * __builtin_amdgcn_rcpf((&s4_c.x)[h] + 1e-16f);

        float c4[8] = {0,0,0,0,0,0,0,0};
#pragma unroll
        for (int mb = 0; mb < 8; ++mb) {
            const bf16x8 wa = *(const bf16x8*)&Wl[mb][l][0];
            const bf16x8 we = *(const bf16x8*)&Wl[8 + mb][l][0];
            const f32x4 ee = __builtin_amdgcn_mfma_f32_16x16x32_bf16(we, xe_c, z, 0, 0, 0);
            const f32x4 hb = __builtin_amdgcn_mfma_f32_16x16x32_bf16(wa, xj_c, z, 0, 0, 0);
            const float a = af[mb >> 1];
            const int s = (mb & 1) * 4;
#pragma unroll
            for (int r = 0; r < 4; ++r)
                c4[s + r] += spf(hb[r] + ee[r]) * a;
        }
#pragma unroll
        for (int s2 = 0; s2 < 2; ++s2) {
            short4 pk = { f2bf(c4[s2*4+0]), f2bf(c4[s2*4+1]), f2bf(c4[s2*4+2]), f2bf(c4[s2*4+3]) };
            *(short4*)&msg[(size_t)d_c * 32 + s2 * 16 + 4 * q] = pk;
        }
        tt = ttn;
        d_c = d_n; xj_c = xj_n; xe_c = xe_n; a4_c = a4_n; s4_c = s4_n;
    }
}

// kred: per node, stream its sorted msg rows, x0.25, +bias -> outp (f32) + outb (bf16)
__global__ __launch_bounds__(256) void kred(
    const int* __restrict__ off, const short* __restrict__ msg, FP bias,
    float* __restrict__ outp, short* __restrict__ outb, int N)
{
    const int lane = threadIdx.x & 31;
    const int sub = threadIdx.x >> 5;
    const float b = bias[lane];
    for (int node = blockIdx.x * 8 + sub; node < N; node += gridDim.x * 8) {
        const int o0 = off[node], o1 = off[node + 1];
        float acc = 0.f;
        for (int p = o0; p < o1; ++p) acc += bf2f(msg[(size_t)p * 32 + lane]);
        const float v = 0.25f * acc + b;
        outp[(size_t)node * 32 + lane] = v;
        outb[(size_t)node * 32 + lane] = f2bf(v);
    }
}

// ---------------------------------------------------------------------------
// kG2v: edge MLP with 1-deep pipeline on the outb/efb gathers. Interleaved
// silu->MFMA per kc slice (hs 5.1 KB; LDS 38.5 KB -> 4 blocks/CU). (256,2).
// ---------------------------------------------------------------------------
__global__ __launch_bounds__(256, 2) void kG2v(
    const short* __restrict__ efb, const int* __restrict__ eidx,
    const short* __restrict__ outb,
    FP W1g, FP W2, FP b1g, FP b2g, float* __restrict__ eout, int E)
{
    __shared__ __align__(16) short W1f[3][8][64][8];   // 24 KB
    __shared__ __align__(16) short W2f[8][64][8];      // 8 KB
    __shared__ float b1l[128];
    __shared__ float b2l[32];
    __shared__ __align__(16) short hs[4][16 * 40];     // 5.1 KB: one kc slice/wave
    const int t = threadIdx.x;
    for (int s = t; s < 3 * 8 * 64; s += 256) {
        const int ks = s >> 9, rem = s & 511, mb = rem >> 6, ll = rem & 63;
        const int c = 16 * mb + (ll & 15);
        const int k0 = ks * 32 + 8 * (ll >> 4);
        bf16x8 f;
#pragma unroll
        for (int j = 0; j < 8; ++j) f[j] = f2bf(W1g[(size_t)(k0 + j) * 128 + c]);
        *(bf16x8*)&W1f[ks][mb][ll][0] = f;
    }
    for (int s = t; s < 8 * 64; s += 256) {
        const int f = s >> 6, ll = s & 63;
        const int kc = f >> 1, m2 = f & 1;
        bf16x8 fr = load_wfrag(W2 + 32 * kc * 32, 32, 16 * m2, ll);
        *(bf16x8*)&W2f[f][ll][0] = fr;
    }
    if (t < 128) b1l[t] = b1g[t];
    if (t < 32)  b2l[t] = b2g[t];
    __syncthreads();

    const int l = t & 63, q = l >> 4, e15 = l & 15, wvb = t >> 6;
    short* hw = &hs[wvb][0];
    const f32x4 z = {0.f, 0.f, 0.f, 0.f};

    const int wv = blockIdx.x * 4 + wvb, nw = gridDim.x * 4, nt = E >> 4;
    int tt = wv;
    bf16x8 xb0_c, xb1_c, xb2_c;
    if (tt < nt) {
        const int e = tt * 16 + e15;
        const int ri = eidx[e], ci = eidx[E + e];
        xb0_c = *(const bf16x8*)&outb[(size_t)ri * 32 + 8 * q];
        xb1_c = *(const bf16x8*)&outb[(size_t)ci * 32 + 8 * q];
        xb2_c = *(const bf16x8*)&efb[(size_t)e * 32 + 8 * q];
    }
    while (tt < nt) {
        const int ttn = tt + nw;
        bf16x8 xb0_n, xb1_n, xb2_n;
        if (ttn < nt) {   // wave-uniform prefetch
            const int en = ttn * 16 + e15;
            const int rn = eidx[en], cn = eidx[E + en];
            xb0_n = *(const bf16x8*)&outb[(size_t)rn * 32 + 8 * q];
            xb1_n = *(const bf16x8*)&outb[(size_t)cn * 32 + 8 * q];
            xb2_n = *(const bf16x8*)&efb[(size_t)en * 32 + 8 * q];
        }
        const int e = tt * 16 + e15;
        f32x4 a1[8] = {z, z, z, z, z, z, z, z};
#pragma unroll
        for (int mb = 0; mb < 8; ++mb) {
            a1[mb] = __builtin_amdgcn_mfma_f32_16x16x32_bf16(*(const bf16x8*)&W1f[0][mb][l][0], xb0_c, a1[mb], 0, 0, 0);
            a1[mb] = __builtin_amdgcn_mfma_f32_16x16x32_bf16(*(const bf16x8*)&W1f[1][mb][l][0], xb1_c, a1[mb], 0, 0, 0);
            a1[mb] = __builtin_amdgcn_mfma_f32_16x16x32_bf16(*(const bf16x8*)&W1f[2][mb][l][0], xb2_c, a1[mb], 0, 0, 0);
        }
        f32x4 oc0 = z, oc1 = z;
#pragma unroll
        for (int kc = 0; kc < 4; ++kc) {
#pragma unroll
            for (int half = 0; half < 2; ++half) {
                const int mb = 2 * kc + half;
                short4 s;
                s.x = f2bf(silu_f(a1[mb][0] + b1l[16 * mb + 4 * q + 0]));
                s.y = f2bf(silu_f(a1[mb][1] + b1l[16 * mb + 4 * q + 1]));
                s.z = f2bf(silu_f(a1[mb][2] + b1l[16 * mb + 4 * q + 2]));
                s.w = f2bf(silu_f(a1[mb][3] + b1l[16 * mb + 4 * q + 3]));
                *(short4*)&hw[e15 * 40 + half * 16 + 4 * q] = s;   // wave-internal, in-order DS
            }
            const bf16x8 hf = *(const bf16x8*)&hw[e15 * 40 + 8 * q];
            const bf16x8 w20 = *(const bf16x8*)&W2f[kc * 2][l][0];
            const bf16x8 w21 = *(const bf16x8*)&W2f[kc * 2 + 1][l][0];
            oc0 = __builtin_amdgcn_mfma_f32_16x16x32_bf16(w20, hf, oc0, 0, 0, 0);
            oc1 = __builtin_amdgcn_mfma_f32_16x16x32_bf16(w21, hf, oc1, 0, 0, 0);
        }
        float4 o0, o1;
#pragma unroll
        for (int r = 0; r < 4; ++r) {
            (&o0.x)[r] = silu_f(oc0[r] + b2l[4 * q + r]);
            (&o1.x)[r] = silu_f(oc1[r] + b2l[16 + 4 * q + r]);
        }
        *(float4*)&eout[(size_t)e * 32 + 4 * q] = o0;
        *(float4*)&eout[(size_t)e * 32 + 16 + 4 * q] = o1;
        tt = ttn;
        xb0_c = xb0_n; xb1_c = xb1_n; xb2_c = xb2_n;
    }
}

extern "C" void kernel_launch(void* const* d_in, const int* in_sizes, int n_in,
                              void* d_out, int out_size, void* d_ws, size_t ws_size,
                              hipStream_t stream)
{
    const float* atom = (const float*)d_in[0];
    const int*   eidx = (const int*)d_in[1];
    const float* efea = (const float*)d_in[2];
    const float* Wg   = (const float*)d_in[6];
    const float* attg = (const float*)d_in[7];
    const float* bias = (const float*)d_in[8];
    const float* gam  = (const float*)d_in[9];
    const float* bet  = (const float*)d_in[10];
    const float* W1g  = (const float*)d_in[11];
    const float* b1g  = (const float*)d_in[12];
    const float* W2g  = (const float*)d_in[13];
    const float* b2g  = (const float*)d_in[14];

    const int N = in_sizes[0] / 32;
    const int E = in_sizes[2] / 32;
    const int NBLK = 4096;
    const int nbs = (N + 255) >> 8;               // scan blocks

    // workspace layout (f32 units, 16B-aligned sections)
    float* ws = (float*)d_ws;
    size_t o = 0;
    float* sbuf   = ws + o;          o += (size_t)4 * N;   // zeroed
    int*   cnt    = (int*)(ws + o);  o += N;               // zeroed
    float* bnsc   = ws + o;          o += 8;
    int*   off    = (int*)(ws + o);  o += (size_t)N + 1;
    o = (o + 3) & ~(size_t)3;
    int*   rank   = (int*)(ws + o);  o += E;
    int*   part   = (int*)(ws + o);  o += (size_t)nbs + 4;
    o = (o + 3) & ~(size_t)3;
    float* bnpart = ws + o;          o += (size_t)NBLK * 16;
    o = (o + 7) & ~(size_t)7;
    short* atomb  = (short*)(ws + o); o += (size_t)N * 16;   // N*32 bf16
    short* efb    = (short*)(ws + o); o += (size_t)E * 16;   // E*32 bf16
    short* outb   = (short*)(ws + o); o += (size_t)N * 16;   // N*32 bf16

    // d_out: [out N*32 f32][eout E*32 f32]; eout region = alpha + msg scratch
    float* outp  = (float*)d_out;
    float* scratch = outp + (size_t)N * 32;
    float* alpha = scratch;                          // 4E f32
    short* msg   = (short*)(scratch + (size_t)4 * E);// E*32 bf16 (sorted messages)
    float* eout  = scratch;                          // written last by kG2v

    hipMemsetAsync(ws, 0, (size_t)5 * N * sizeof(float), stream);  // sbuf,cnt

    const int n4e = 4 * E;
    kprep<<<2048, 256, 0, stream>>>(atom, efea, eidx, atomb, efb, cnt, rank, N * 8, E * 8, E);
    kscanA<<<nbs, 256, 0, stream>>>(cnt, part, N);
    kscanB<<<1, 1024, 0, stream>>>(part, nbs);
    kscanC<<<nbs, 256, 0, stream>>>(cnt, part, off, N);
    kBc  <<<NBLK, 256, 0, stream>>>(efb, eidx, atomb, Wg, attg, alpha, bnpart, E);
    k2_bn<<<1, 256, 0, stream>>>(bnpart, NBLK, gam, bet, bnsc, E);
    k34  <<<(n4e + 255) / 256, 256, 0, stream>>>(alpha, eidx, sbuf, bnsc, E);
    kmsg3<<<4096, 256, 0, stream>>>(efb, eidx, atomb, off, rank, Wg, alpha, sbuf, msg, E);
    kred <<<4096, 256, 0, stream>>>(off, msg, bias, outp, outb, N);
    kG2v <<<2048, 256, 0, stream>>>(efb, eidx, outb, W1g, W2g, b1g, b2g, eout, E);
}

// Round 20
// 353.741 us; speedup vs baseline: 1.2388x; 1.0316x over previous
//
#include <hip/hip_runtime.h>

typedef __attribute__((ext_vector_type(8))) short bf16x8;
typedef __attribute__((ext_vector_type(4))) float f32x4;

#define FP const float* __restrict__

__device__ __forceinline__ short f2bf(float f) {
    unsigned u = __float_as_uint(f);
    u += 0x7fffu + ((u >> 16) & 1u);
    return (short)(u >> 16);
}
__device__ __forceinline__ float bf2f(short s) {
    return __uint_as_float(((unsigned)(unsigned short)s) << 16);
}
__device__ __forceinline__ float v_exp2(float x) { float r; asm("v_exp_f32 %0, %1" : "=v"(r) : "v"(x)); return r; }
__device__ __forceinline__ float v_log2(float x) { float r; asm("v_log_f32 %0, %1" : "=v"(r) : "v"(x)); return r; }

__device__ __forceinline__ float fexp(float x) { return v_exp2(1.44269504f * x); }
__device__ __forceinline__ float sp(float x) {         // exact softplus (BN/softmax path)
    return fmaxf(x, 0.f) + 0.69314718f * v_log2(1.f + v_exp2(-1.44269504f * fabsf(x)));
}
// fast softplus: cubic fit of log2(1+t), abs err ~1e-3 (<< bf16 rounding).
__device__ __forceinline__ float spf(float x) {
    const float t = v_exp2(-1.44269504f * fabsf(x));
    const float p = t * (1.419f + t * (-0.573f + 0.154f * t));
    return fmaxf(x, 0.f) + 0.69314718f * p;
}
__device__ __forceinline__ float silu_f(float x) {
    return x * __builtin_amdgcn_rcpf(1.f + v_exp2(-1.44269504f * x));
}

// A-operand = W^T tile: lane l holds W[k, c0+(l&15)], k = 8*(l>>4)+j. W is [32+,ld] f32.
__device__ __forceinline__ bf16x8 load_wfrag(FP w, int ld, int c0, int l) {
    const int c = c0 + (l & 15);
    const int k0 = 8 * (l >> 4);
    bf16x8 f;
#pragma unroll
    for (int j = 0; j < 8; ++j) f[j] = f2bf(w[(k0 + j) * ld + c]);
    return f;
}
// B-operand from f32 row-major x[R,32]: lane l holds x[r0+(l&15), 8*(l>>4)+j]
__device__ __forceinline__ bf16x8 load_xfrag32(FP x, int r0, int l) {
    const int row = r0 + (l & 15);
    const float* p = x + (size_t)row * 32 + 8 * (l >> 4);
    const float4 a = *(const float4*)p;
    const float4 b = *(const float4*)(p + 4);
    bf16x8 f;
    f[0]=f2bf(a.x); f[1]=f2bf(a.y); f[2]=f2bf(a.z); f[3]=f2bf(a.w);
    f[4]=f2bf(b.x); f[5]=f2bf(b.y); f[6]=f2bf(b.z); f[7]=f2bf(b.w);
    return f;
}

// ---------------------------------------------------------------------------
// kprep: bf16-ize atom (N*32) + in-degree histogram/rank. (efb pass deleted:
// consumers read ef f32 directly — same f2bf rounding, inputs L3-resident.)
// ---------------------------------------------------------------------------
__global__ __launch_bounds__(256) void kprep(
    FP atom, const int* __restrict__ eidx,
    short* __restrict__ atomb,
    int* __restrict__ cnt, int* __restrict__ rank,
    int nA4, int E)
{
    const int stride = gridDim.x * 256;
    const int tot = nA4 + E;
    for (int t = blockIdx.x * 256 + threadIdx.x; t < tot; t += stride) {
        if (t < nA4) {
            const float4 v = ((const float4*)atom)[t];
            short4 s = { f2bf(v.x), f2bf(v.y), f2bf(v.z), f2bf(v.w) };
            ((short4*)atomb)[t] = s;
        } else {
            const int e = t - nA4;
            rank[e] = atomicAdd(&cnt[eidx[e]], 1);
        }
    }
}

// kscanA: per-block sum of cnt -> part[b]
__global__ __launch_bounds__(256) void kscanA(
    const int* __restrict__ cnt, int* __restrict__ part, int N)
{
    __shared__ int wsum[4];
    const int t = threadIdx.x;
    const int i = blockIdx.x * 256 + t;
    int v = (i < N) ? cnt[i] : 0;
#pragma unroll
    for (int d = 1; d < 64; d <<= 1) v += __shfl_xor(v, d);
    if ((t & 63) == 0) wsum[t >> 6] = v;
    __syncthreads();
    if (t == 0) part[blockIdx.x] = wsum[0] + wsum[1] + wsum[2] + wsum[3];
}

// kscanB: single block exclusive scan over nb partials (nb <= 1024)
__global__ __launch_bounds__(1024) void kscanB(
    int* __restrict__ part, int nb)
{
    __shared__ int pa[1024], pb[1024];
    const int t = threadIdx.x;
    pa[t] = (t < nb) ? part[t] : 0;
    __syncthreads();
    int* src = pa; int* dst = pb;
#pragma unroll
    for (int d = 1; d < 1024; d <<= 1) {
        int v = src[t];
        if (t >= d) v += src[t - d];
        dst[t] = v;
        __syncthreads();
        int* tmp = src; src = dst; dst = tmp;
    }
    if (t < nb) part[t] = (t == 0) ? 0 : src[t - 1];
}

// kscanC: block-local scan + base -> off[i]; last element writes off[N]
__global__ __launch_bounds__(256) void kscanC(
    const int* __restrict__ cnt, const int* __restrict__ part,
    int* __restrict__ off, int N)
{
    __shared__ int pa[256], pb[256];
    const int t = threadIdx.x;
    const int i = blockIdx.x * 256 + t;
    const int c = (i < N) ? cnt[i] : 0;
    pa[t] = c;
    __syncthreads();
    int* src = pa; int* dst = pb;
#pragma unroll
    for (int d = 1; d < 256; d <<= 1) {
        int v = src[t];
        if (t >= d) v += src[t - d];
        dst[t] = v;
        __syncthreads();
        int* tmp = src; src = dst; dst = tmp;
    }
    const int incl = src[t];
    const int base = part[blockIdx.x];
    if (i < N) off[i] = base + incl - c;
    if (i == N - 1) off[N] = base + incl;
}

// ---------------------------------------------------------------------------
// kBc: single-tile, (256,8) occupancy form (R19). ef read directly as f32.
// ---------------------------------------------------------------------------
__global__ __launch_bounds__(256, 8) void kBc(
    FP ef, const int* __restrict__ eidx,
    const short* __restrict__ atomb, FP Wg, FP attg,
    float* __restrict__ alpha, float* __restrict__ bnpart, int E)
{
    __shared__ float attl[256];
    __shared__ __align__(16) short Wl[16][64][8];   // 16 KB
    __shared__ float bnred[4][8];
    const int t = threadIdx.x;
    if (t < 64) ((float4*)attl)[t] = ((const float4*)attg)[t];
    for (int s = t; s < 1024; s += 256) {
        const int f = s >> 6, ll = s & 63;
        FP src = (f < 8) ? Wg : (Wg + 32 * 128);
        bf16x8 fr = load_wfrag(src, 128, 16 * (f & 7), ll);
        *(bf16x8*)&Wl[f][ll][0] = fr;
    }
    __syncthreads();

    const int l = t & 63, q = l >> 4, e15 = l & 15, wvb = t >> 6;
    const int wv = blockIdx.x * 4 + wvb, nw = gridDim.x * 4;
    const f32x4 z = {0.f, 0.f, 0.f, 0.f};
    float bs[4] = {0,0,0,0}, bq2[4] = {0,0,0,0};

    const int nt = E >> 4;
    for (int tt = wv; tt < nt; tt += nw) {
        const int tb = tt * 16;
        const int e = tb + e15;
        const int i = eidx[e], j = eidx[E + e];
        const bf16x8 xi = *(const bf16x8*)&atomb[(size_t)i * 32 + 8 * q];
        const bf16x8 xj = *(const bf16x8*)&atomb[(size_t)j * 32 + 8 * q];
        const bf16x8 xe = load_xfrag32(ef, tb, l);

        float ph[4] = {0,0,0,0};
#pragma unroll
        for (int mb = 0; mb < 8; ++mb) {
            const bf16x8 wa = *(const bf16x8*)&Wl[mb][l][0];
            const bf16x8 we = *(const bf16x8*)&Wl[8 + mb][l][0];
            const f32x4 ee = __builtin_amdgcn_mfma_f32_16x16x32_bf16(we, xe, z, 0, 0, 0);
            const f32x4 ha = __builtin_amdgcn_mfma_f32_16x16x32_bf16(wa, xi, z, 0, 0, 0);
            const f32x4 hb = __builtin_amdgcn_mfma_f32_16x16x32_bf16(wa, xj, z, 0, 0, 0);
            const int h = mb >> 1;
            const int c0 = (mb & 1) * 16 + 4 * q;
#pragma unroll
            for (int r = 0; r < 4; ++r) {
                ph[h] += spf(ha[r] + ee[r]) * attl[h * 64 + c0 + r]
                       + spf(hb[r] + ee[r]) * attl[h * 64 + 32 + c0 + r];
            }
        }
        float4 a0v;
#pragma unroll
        for (int h = 0; h < 4; ++h) {
            float v = ph[h];
            v += __shfl_xor(v, 16);
            v += __shfl_xor(v, 32);
            (&a0v.x)[h] = sp(v);
        }
        if (q == 0) {
            *(float4*)&alpha[(size_t)e * 4] = a0v;
#pragma unroll
            for (int h = 0; h < 4; ++h) {
                const float a0 = (&a0v.x)[h];
                bs[h] += a0; bq2[h] += a0 * a0;
            }
        }
    }
#pragma unroll
    for (int h = 0; h < 4; ++h) {
        float v = bs[h], w = bq2[h];
#pragma unroll
        for (int d = 1; d < 64; d <<= 1) { v += __shfl_xor(v, d); w += __shfl_xor(w, d); }
        if (l == 0) { bnred[wvb][h] = v; bnred[wvb][4 + h] = w; }
    }
    __syncthreads();
    if (t < 8) {
        const float s = bnred[0][t] + bnred[1][t] + bnred[2][t] + bnred[3][t];
        bnpart[(size_t)blockIdx.x * 16 + t] = s;
    }
}

// k2: reduce per-block BN partials, finalize scale/shift
__global__ __launch_bounds__(256) void k2_bn(
    const float* __restrict__ bnpart, int nblk, FP gam, FP bet,
    float* __restrict__ bnsc, int E)
{
    __shared__ float red[256];
    const int t = threadIdx.x;
    const int h = t & 7, c = t >> 3;
    float s = 0.f;
    for (int b = c; b < nblk; b += 32) s += bnpart[(size_t)b * 16 + h];
    red[t] = s;
    __syncthreads();
    if (t < 8) {
        float acc = 0.f;
#pragma unroll
        for (int c2 = 0; c2 < 32; ++c2) acc += red[c2 * 8 + t];
        red[t] = acc;
    }
    __syncthreads();
    if (t < 4) {
        const float inv = 1.f / (float)E;
        const float mu  = red[t] * inv;
        const float var = red[4 + t] * inv - mu * mu;
        const float scl = gam[t] * rsqrtf(var + 1e-5f);
        bnsc[t] = scl;
        bnsc[4 + t] = bet[t] - mu * scl;
    }
}

// k34: alpha -> ex = exp(sp(scale*alpha+shift)) in place; distributed seg-sum.
__global__ __launch_bounds__(256) void k34(
    float* __restrict__ alpha, const int* __restrict__ eidx,
    float* __restrict__ sbuf, const float* __restrict__ bnsc, int E)
{
    const int t = blockIdx.x * 256 + threadIdx.x;
    if (t >= 4 * E) return;
    const int e = t >> 2, h = t & 3;
    const float a1 = sp(bnsc[h] * alpha[t] + bnsc[4 + h]);
    const float ex = fexp(a1);
    alpha[t] = ex;
    atomicAdd(&sbuf[eidx[e] * 4 + h], ex);
}

// ---------------------------------------------------------------------------
// kmsg3: 1-deep software pipeline; ef read directly as f32; scatter store.
// ---------------------------------------------------------------------------
__global__ __launch_bounds__(256, 4) void kmsg3(
    FP ef, const int* __restrict__ eidx,
    const short* __restrict__ atomb, const int* __restrict__ off,
    const int* __restrict__ rank, FP Wg,
    const float* __restrict__ alpha, const float* __restrict__ sbuf,
    short* __restrict__ msg, int E)
{
    __shared__ __align__(16) short Wl[16][64][8];   // 16 KB
    const int t = threadIdx.x;
    for (int s = t; s < 1024; s += 256) {
        const int f = s >> 6, ll = s & 63;
        FP src = (f < 8) ? Wg : (Wg + 32 * 128);
        bf16x8 fr = load_wfrag(src, 128, 16 * (f & 7), ll);
        *(bf16x8*)&Wl[f][ll][0] = fr;
    }
    __syncthreads();

    const int l = t & 63, q = l >> 4, e15 = l & 15;
    const int wv = blockIdx.x * 4 + (t >> 6), nw = gridDim.x * 4;
    const f32x4 z = {0.f, 0.f, 0.f, 0.f};

    const int nt = E >> 4;
    int tt = wv;
    bf16x8 xj_c, xe_c;
    float4 a4_c, s4_c;
    int d_c = 0;
    if (tt < nt) {
        const int e = tt * 16 + e15;
        const int i = eidx[e], j = eidx[E + e];
        d_c = off[i] + rank[e];
        xj_c = *(const bf16x8*)&atomb[(size_t)j * 32 + 8 * q];
        xe_c = load_xfrag32(ef, tt * 16, l);
        a4_c = *(const float4*)&alpha[(size_t)e * 4];
        s4_c = *(const float4*)&sbuf[(size_t)i * 4];
    }
    while (tt < nt) {
        const int ttn = tt + nw;
        bf16x8 xj_n, xe_n;
        float4 a4_n, s4_n;
        int d_n = 0;
        if (ttn < nt) {   // wave-uniform prefetch
            const int en = ttn * 16 + e15;
            const int in_ = eidx[en], jn = eidx[E + en];
            d_n = off[in_] + rank[en];
            xj_n = *(const bf16x8*)&atomb[(size_t)jn * 32 + 8 * q];
            xe_n = load_xfrag32(ef, ttn * 16, l);
            a4_n = *(const float4*)&alpha[(size_t)en * 4];
            s4_n = *(const float4*)&sbuf[(size_t)in_ * 4];
        }
        float af[4];
#pragma unroll
        for (int h = 0; h < 4; ++h)
            af[h] = (&a4_c.x)[h] * __builtin_amdgcn_rcpf((&s4_c.x)[h] + 1e-16f);

        float c4[8] = {0,0,0,0,0,0,0,0};
#pragma unroll
        for (int mb = 0; mb < 8; ++mb) {
            const bf16x8 wa = *(const bf16x8*)&Wl[mb][l][0];
            const bf16x8 we = *(const bf16x8*)&Wl[8 + mb][l][0];
            const f32x4 ee = __builtin_amdgcn_mfma_f32_16x16x32_bf16(we, xe_c, z, 0, 0, 0);
            const f32x4 hb = __builtin_amdgcn_mfma_f32_16x16x32_bf16(wa, xj_c, z, 0, 0, 0);
            const float a = af[mb >> 1];
            const int s = (mb & 1) * 4;
#pragma unroll
            for (int r = 0; r < 4; ++r)
                c4[s + r] += spf(hb[r] + ee[r]) * a;
        }
#pragma unroll
        for (int s2 = 0; s2 < 2; ++s2) {
            short4 pk = { f2bf(c4[s2*4+0]), f2bf(c4[s2*4+1]), f2bf(c4[s2*4+2]), f2bf(c4[s2*4+3]) };
            *(short4*)&msg[(size_t)d_c * 32 + s2 * 16 + 4 * q] = pk;
        }
        tt = ttn;
        d_c = d_n; xj_c = xj_n; xe_c = xe_n; a4_c = a4_n; s4_c = s4_n;
    }
}

// kred: per node, stream its sorted msg rows, x0.25, +bias -> outp (f32) + outb (bf16)
__global__ __launch_bounds__(256) void kred(
    const int* __restrict__ off, const short* __restrict__ msg, FP bias,
    float* __restrict__ outp, short* __restrict__ outb, int N)
{
    const int lane = threadIdx.x & 31;
    const int sub = threadIdx.x >> 5;
    const float b = bias[lane];
    for (int node = blockIdx.x * 8 + sub; node < N; node += gridDim.x * 8) {
        const int o0 = off[node], o1 = off[node + 1];
        float acc = 0.f;
        for (int p = o0; p < o1; ++p) acc += bf2f(msg[(size_t)p * 32 + lane]);
        const float v = 0.25f * acc + b;
        outp[(size_t)node * 32 + lane] = v;
        outb[(size_t)node * 32 + lane] = f2bf(v);
    }
}

// ---------------------------------------------------------------------------
// kG2v: edge MLP with 1-deep pipeline; ef read directly as f32. (256,2).
// ---------------------------------------------------------------------------
__global__ __launch_bounds__(256, 2) void kG2v(
    FP ef, const int* __restrict__ eidx,
    const short* __restrict__ outb,
    FP W1g, FP W2, FP b1g, FP b2g, float* __restrict__ eout, int E)
{
    __shared__ __align__(16) short W1f[3][8][64][8];   // 24 KB
    __shared__ __align__(16) short W2f[8][64][8];      // 8 KB
    __shared__ float b1l[128];
    __shared__ float b2l[32];
    __shared__ __align__(16) short hs[4][16 * 40];     // 5.1 KB: one kc slice/wave
    const int t = threadIdx.x;
    for (int s = t; s < 3 * 8 * 64; s += 256) {
        const int ks = s >> 9, rem = s & 511, mb = rem >> 6, ll = rem & 63;
        const int c = 16 * mb + (ll & 15);
        const int k0 = ks * 32 + 8 * (ll >> 4);
        bf16x8 f;
#pragma unroll
        for (int j = 0; j < 8; ++j) f[j] = f2bf(W1g[(size_t)(k0 + j) * 128 + c]);
        *(bf16x8*)&W1f[ks][mb][ll][0] = f;
    }
    for (int s = t; s < 8 * 64; s += 256) {
        const int f = s >> 6, ll = s & 63;
        const int kc = f >> 1, m2 = f & 1;
        bf16x8 fr = load_wfrag(W2 + 32 * kc * 32, 32, 16 * m2, ll);
        *(bf16x8*)&W2f[f][ll][0] = fr;
    }
    if (t < 128) b1l[t] = b1g[t];
    if (t < 32)  b2l[t] = b2g[t];
    __syncthreads();

    const int l = t & 63, q = l >> 4, e15 = l & 15, wvb = t >> 6;
    short* hw = &hs[wvb][0];
    const f32x4 z = {0.f, 0.f, 0.f, 0.f};

    const int wv = blockIdx.x * 4 + wvb, nw = gridDim.x * 4, nt = E >> 4;
    int tt = wv;
    bf16x8 xb0_c, xb1_c, xb2_c;
    if (tt < nt) {
        const int e = tt * 16 + e15;
        const int ri = eidx[e], ci = eidx[E + e];
        xb0_c = *(const bf16x8*)&outb[(size_t)ri * 32 + 8 * q];
        xb1_c = *(const bf16x8*)&outb[(size_t)ci * 32 + 8 * q];
        xb2_c = load_xfrag32(ef, tt * 16, l);
    }
    while (tt < nt) {
        const int ttn = tt + nw;
        bf16x8 xb0_n, xb1_n, xb2_n;
        if (ttn < nt) {   // wave-uniform prefetch
            const int en = ttn * 16 + e15;
            const int rn = eidx[en], cn = eidx[E + en];
            xb0_n = *(const bf16x8*)&outb[(size_t)rn * 32 + 8 * q];
            xb1_n = *(const bf16x8*)&outb[(size_t)cn * 32 + 8 * q];
            xb2_n = load_xfrag32(ef, ttn * 16, l);
        }
        const int e = tt * 16 + e15;
        f32x4 a1[8] = {z, z, z, z, z, z, z, z};
#pragma unroll
        for (int mb = 0; mb < 8; ++mb) {
            a1[mb] = __builtin_amdgcn_mfma_f32_16x16x32_bf16(*(const bf16x8*)&W1f[0][mb][l][0], xb0_c, a1[mb], 0, 0, 0);
            a1[mb] = __builtin_amdgcn_mfma_f32_16x16x32_bf16(*(const bf16x8*)&W1f[1][mb][l][0], xb1_c, a1[mb], 0, 0, 0);
            a1[mb] = __builtin_amdgcn_mfma_f32_16x16x32_bf16(*(const bf16x8*)&W1f[2][mb][l][0], xb2_c, a1[mb], 0, 0, 0);
        }
        f32x4 oc0 = z, oc1 = z;
#pragma unroll
        for (int kc = 0; kc < 4; ++kc) {
#pragma unroll
            for (int half = 0; half < 2; ++half) {
                const int mb = 2 * kc + half;
                short4 s;
                s.x = f2bf(silu_f(a1[mb][0] + b1l[16 * mb + 4 * q + 0]));
                s.y = f2bf(silu_f(a1[mb][1] + b1l[16 * mb + 4 * q + 1]));
                s.z = f2bf(silu_f(a1[mb][2] + b1l[16 * mb + 4 * q + 2]));
                s.w = f2bf(silu_f(a1[mb][3] + b1l[16 * mb + 4 * q + 3]));
                *(short4*)&hw[e15 * 40 + half * 16 + 4 * q] = s;   // wave-internal, in-order DS
            }
            const bf16x8 hf = *(const bf16x8*)&hw[e15 * 40 + 8 * q];
            const bf16x8 w20 = *(const bf16x8*)&W2f[kc * 2][l][0];
            const bf16x8 w21 = *(const bf16x8*)&W2f[kc * 2 + 1][l][0];
            oc0 = __builtin_amdgcn_mfma_f32_16x16x32_bf16(w20, hf, oc0, 0, 0, 0);
            oc1 = __builtin_amdgcn_mfma_f32_16x16x32_bf16(w21, hf, oc1, 0, 0, 0);
        }
        float4 o0, o1;
#pragma unroll
        for (int r = 0; r < 4; ++r) {
            (&o0.x)[r] = silu_f(oc0[r] + b2l[4 * q + r]);
            (&o1.x)[r] = silu_f(oc1[r] + b2l[16 + 4 * q + r]);
        }
        *(float4*)&eout[(size_t)e * 32 + 4 * q] = o0;
        *(float4*)&eout[(size_t)e * 32 + 16 + 4 * q] = o1;
        tt = ttn;
        xb0_c = xb0_n; xb1_c = xb1_n; xb2_c = xb2_n;
    }
}

extern "C" void kernel_launch(void* const* d_in, const int* in_sizes, int n_in,
                              void* d_out, int out_size, void* d_ws, size_t ws_size,
                              hipStream_t stream)
{
    const float* atom = (const float*)d_in[0];
    const int*   eidx = (const int*)d_in[1];
    const float* efea = (const float*)d_in[2];
    const float* Wg   = (const float*)d_in[6];
    const float* attg = (const float*)d_in[7];
    const float* bias = (const float*)d_in[8];
    const float* gam  = (const float*)d_in[9];
    const float* bet  = (const float*)d_in[10];
    const float* W1g  = (const float*)d_in[11];
    const float* b1g  = (const float*)d_in[12];
    const float* W2g  = (const float*)d_in[13];
    const float* b2g  = (const float*)d_in[14];

    const int N = in_sizes[0] / 32;
    const int E = in_sizes[2] / 32;
    const int NBLK = 4096;
    const int nbs = (N + 255) >> 8;               // scan blocks

    // workspace layout (f32 units, 16B-aligned sections)
    float* ws = (float*)d_ws;
    size_t o = 0;
    float* sbuf   = ws + o;          o += (size_t)4 * N;   // zeroed
    int*   cnt    = (int*)(ws + o);  o += N;               // zeroed
    float* bnsc   = ws + o;          o += 8;
    int*   off    = (int*)(ws + o);  o += (size_t)N + 1;
    o = (o + 3) & ~(size_t)3;
    int*   rank   = (int*)(ws + o);  o += E;
    int*   part   = (int*)(ws + o);  o += (size_t)nbs + 4;
    o = (o + 3) & ~(size_t)3;
    float* bnpart = ws + o;          o += (size_t)NBLK * 16;
    o = (o + 7) & ~(size_t)7;
    short* atomb  = (short*)(ws + o); o += (size_t)N * 16;   // N*32 bf16
    short* outb   = (short*)(ws + o); o += (size_t)N * 16;   // N*32 bf16

    // d_out: [out N*32 f32][eout E*32 f32]; eout region = alpha + msg scratch
    float* outp  = (float*)d_out;
    float* scratch = outp + (size_t)N * 32;
    float* alpha = scratch;                          // 4E f32
    short* msg   = (short*)(scratch + (size_t)4 * E);// E*32 bf16 (sorted messages)
    float* eout  = scratch;                          // written last by kG2v

    hipMemsetAsync(ws, 0, (size_t)5 * N * sizeof(float), stream);  // sbuf,cnt

    const int n4e = 4 * E;
    kprep<<<2048, 256, 0, stream>>>(atom, eidx, atomb, cnt, rank, N * 8, E);
    kscanA<<<nbs, 256, 0, stream>>>(cnt, part, N);
    kscanB<<<1, 1024, 0, stream>>>(part, nbs);
    kscanC<<<nbs, 256, 0, stream>>>(cnt, part, off, N);
    kBc  <<<NBLK, 256, 0, stream>>>(efea, eidx, atomb, Wg, attg, alpha, bnpart, E);
    k2_bn<<<1, 256, 0, stream>>>(bnpart, NBLK, gam, bet, bnsc, E);
    k34  <<<(n4e + 255) / 256, 256, 0, stream>>>(alpha, eidx, sbuf, bnsc, E);
    kmsg3<<<4096, 256, 0, stream>>>(efea, eidx, atomb, off, rank, Wg, alpha, sbuf, msg, E);
    kred <<<4096, 256, 0, stream>>>(off, msg, bias, outp, outb, N);
    kG2v <<<2048, 256, 0, stream>>>(efea, eidx, outb, W1g, W2g, b1g, b2g, eout, E);
}